// Round 11
// baseline (1401.972 us; speedup 1.0000x reference)
//
#include <hip/hip_runtime.h>
#include <math.h>

#define N 16384
#define D 512
#define K 1024
#define NUM_ITERS 10
#define TEMPERATURE 0.1f
#define CONCENTRATION 0.1f
#define EPS 1e-6f

typedef unsigned short ushort_t;
typedef unsigned int uint_t;
typedef unsigned long long u64;
typedef __attribute__((ext_vector_type(4))) float floatx4;
typedef __attribute__((ext_vector_type(8))) short shortx8;

#define BM 128
#define BN 128
#define BK 32

// ---------- bf16 split helpers ----------
__device__ inline ushort_t f2bf(float f) {
    unsigned b = __float_as_uint(f);
    b += 0x7FFFu + ((b >> 16) & 1u);   // RNE
    return (ushort_t)(b >> 16);
}
__device__ inline float bf2f(ushort_t h) { return __uint_as_float(((unsigned)h) << 16); }

__device__ inline unsigned ford(float f) {   // order-preserving float->uint
    unsigned b = __float_as_uint(f);
    return (b & 0x80000000u) ? ~b : (b | 0x80000000u);
}

__device__ inline void f4add(float4& a, const float4& b) {
    a.x += b.x; a.y += b.y; a.z += b.z; a.w += b.w;
}

__device__ inline void gld16(const void* g, void* l) {
    __builtin_amdgcn_global_load_lds(
        (const __attribute__((address_space(1))) void*)(uintptr_t)(g),
        (__attribute__((address_space(3))) void*)(uintptr_t)(l), 16, 0, 0);
}

// ---------- split fp32 -> (hi, lo) bf16 (A only, once) ----------
__global__ void split_kernel(const float* __restrict__ x, ushort_t* __restrict__ hi,
                             ushort_t* __restrict__ lo, int n4) {
    int i = blockIdx.x * 256 + threadIdx.x;
    if (i >= n4) return;
    float4 v = ((const float4*)x)[i];
    ushort_t h0 = f2bf(v.x), h1 = f2bf(v.y), h2 = f2bf(v.z), h3 = f2bf(v.w);
    ushort4 hv = {h0, h1, h2, h3};
    ushort4 lv = {f2bf(v.x - bf2f(h0)), f2bf(v.y - bf2f(h1)),
                  f2bf(v.z - bf2f(h2)), f2bf(v.w - bf2f(h3))};
    ((ushort4*)hi)[i] = hv;
    ((ushort4*)lo)[i] = lv;
}

// ---------- row sum-of-squares for INITIAL centroids only ----------
__global__ void rowsq_kernel(const float* __restrict__ x, float* __restrict__ out, int rows) {
    int row = blockIdx.x * 4 + (threadIdx.x >> 6);
    int lane = threadIdx.x & 63;
    if (row >= rows) return;
    const float* r = x + (size_t)row * D;
    float s = 0.f;
    for (int i = lane; i < D; i += 64) { float v = r[i]; s += v * v; }
    for (int off = 32; off > 0; off >>= 1) s += __shfl_down(s, off, 64);
    if (lane == 0) out[row] = s;
}

// ---------- MFMA assign (16x16x32, XOR-swizzled LDS — R9-verified) ----------
// + fused panel-completion conversion: the 8th col-block of each row panel
//   converts best->ids16 (atomicExch also resets best to ~0 for next iter).
__global__ __launch_bounds__(256) void assign_mfma(
    const ushort_t* __restrict__ Ah, const ushort_t* __restrict__ Al,
    const ushort_t* __restrict__ Bh, const ushort_t* __restrict__ Bl,
    const float* __restrict__ csq, u64* __restrict__ best,
    ushort_t* __restrict__ ids16, int* __restrict__ panel_cnt)
{
    __shared__ __align__(16) ushort_t sAh[BM * BK];
    __shared__ __align__(16) ushort_t sAl[BM * BK];
    __shared__ __align__(16) ushort_t sBh[BN * BK];
    __shared__ __align__(16) ushort_t sBl[BN * BK];
    __shared__ int last_flag;

    const int tid = threadIdx.x;
    const int lane = tid & 63;
    const int wave = tid >> 6;
    const int wr = wave >> 1, wc = wave & 1;     // 2x2 wave grid, wave tile 64x64
    const int quad = lane >> 4, l16 = lane & 15;

    const int q = (int)blockIdx.x;
    const int xid = q & 7;
    const int s = q >> 3;
    const int brow = ((s >> 3) << 3) + xid;
    const int bcol = s & 7;
    const int row0 = brow * BM, col0 = bcol * BN;

    floatx4 acc[4][4];
#pragma unroll
    for (int a = 0; a < 4; ++a)
#pragma unroll
        for (int b = 0; b < 4; ++b) acc[a][b] = (floatx4){0.f, 0.f, 0.f, 0.f};

    // staging: slot tid / tid+256; row = c>>2, kb = (c&3) ^ ((row>>1)&3)
    const int r_a = tid >> 2;
    const int dp = (((tid & 3) ^ ((r_a >> 1) & 3))) * 8;

    for (int d0 = 0; d0 < D; d0 += BK) {
        __syncthreads();
        {
            const size_t ga0 = (size_t)(row0 + r_a) * D + d0 + dp;
            const size_t ga1 = (size_t)(row0 + r_a + 64) * D + d0 + dp;
            const size_t gb0 = (size_t)(col0 + r_a) * D + d0 + dp;
            const size_t gb1 = (size_t)(col0 + r_a + 64) * D + d0 + dp;
            const int l0 = tid * 8;
            const int l1 = (tid + 256) * 8;
            gld16(Ah + ga0, sAh + l0); gld16(Ah + ga1, sAh + l1);
            gld16(Al + ga0, sAl + l0); gld16(Al + ga1, sAl + l1);
            gld16(Bh + gb0, sBh + l0); gld16(Bh + gb1, sBh + l1);
            gld16(Bl + gb0, sBl + l0); gld16(Bl + gb1, sBl + l1);
        }
        __syncthreads();

        shortx8 fah[4], fal[4], fbh[4], fbl[4];
#pragma unroll
        for (int t = 0; t < 4; ++t) {
            const int ar = wr * 64 + t * 16 + l16;
            const int bc = wc * 64 + t * 16 + l16;
            const int qa = (quad ^ ((ar >> 1) & 3)) * 8;
            const int qb = (quad ^ ((bc >> 1) & 3)) * 8;
            fah[t] = *(const shortx8*)&sAh[ar * BK + qa];
            fal[t] = *(const shortx8*)&sAl[ar * BK + qa];
            fbh[t] = *(const shortx8*)&sBh[bc * BK + qb];
            fbl[t] = *(const shortx8*)&sBl[bc * BK + qb];
        }
#pragma unroll
        for (int i = 0; i < 4; ++i)
#pragma unroll
            for (int j = 0; j < 4; ++j) {
                acc[i][j] = __builtin_amdgcn_mfma_f32_16x16x32_bf16(fah[i], fbh[j], acc[i][j], 0, 0, 0);
                acc[i][j] = __builtin_amdgcn_mfma_f32_16x16x32_bf16(fah[i], fbl[j], acc[i][j], 0, 0, 0);
                acc[i][j] = __builtin_amdgcn_mfma_f32_16x16x32_bf16(fal[i], fbh[j], acc[i][j], 0, 0, 0);
            }
    }

    float csqv[4];
#pragma unroll
    for (int j = 0; j < 4; ++j) csqv[j] = csq[col0 + wc * 64 + j * 16 + l16];

    const int k0 = col0 + wc * 64 + l16;
#pragma unroll
    for (int i = 0; i < 4; ++i) {
#pragma unroll
        for (int r = 0; r < 4; ++r) {
            float bv = csqv[0] - 2.0f * acc[i][0][r];
            int bk = k0;
#pragma unroll
            for (int j = 1; j < 4; ++j) {
                float v = csqv[j] - 2.0f * acc[i][j][r];
                int kk = k0 + j * 16;
                if (v < bv || (v == bv && kk < bk)) { bv = v; bk = kk; }
            }
#pragma unroll
            for (int m = 1; m < 16; m <<= 1) {
                float ov = __shfl_xor(bv, m, 64);
                int ok = __shfl_xor(bk, m, 64);
                if (ov < bv || (ov == bv && ok < bk)) { bv = ov; bk = ok; }
            }
            if (l16 == 0) {
                int p = row0 + wr * 64 + i * 16 + quad * 4 + r;
                u64 pk = ((u64)ford(bv) << 32) | (unsigned)bk;
                atomicMin(&best[p], pk);
            }
        }
    }

    // ---- panel-completion gate: 8th finishing col-block converts the panel ----
    __syncthreads();                 // all waves' atomicMin issued & drained
    if (tid == 0) {
        __threadfence();             // release our mins before count
        int old = atomicAdd(&panel_cnt[brow], 1);
        last_flag = (old == 7);
    }
    __syncthreads();
    if (last_flag) {
        __threadfence();             // acquire other blocks' mins
        if (tid < BM) {
            int p = row0 + tid;
            u64 v = atomicExch(&best[p], ~0ull);   // read final min + reset
            ids16[p] = (ushort_t)(v & 0xFFFFull);
        }
        if (tid == 0) atomicExch(&panel_cnt[brow], 0);
    }
}

// ======== round-based gather-then-process segment reduce (u16 ids) ========
#define CU_WAVES 8
#define CHUNKS (N / 128)          // 128
#define ROUNDS 4
#define WIN (CHUNKS / ROUNDS)     // 32 chunks/round
#define CPW (WIN / CU_WAVES)      // 4 chunks per wave per round

__global__ __launch_bounds__(512) void cluster_update(
    const float* __restrict__ feats, const uint_t* __restrict__ ids32,
    float* __restrict__ cent, ushort_t* __restrict__ Bh, ushort_t* __restrict__ Bl,
    float* __restrict__ csq)
{
    __shared__ int list[CU_WAVES][CPW * 128];
    __shared__ int lcnt[CU_WAVES];
    __shared__ float4 part[CU_WAVES][64][2];
    __shared__ int pcnt_s[CU_WAVES];

    const int tid = threadIdx.x;
    const int lane = tid & 63;
    const int wave = tid >> 6;
    const int k = (int)blockIdx.x;

    float4 a0 = {0.f, 0.f, 0.f, 0.f}, a1 = {0.f, 0.f, 0.f, 0.f};
    int cnttot = 0;

    for (int round = 0; round < ROUNDS; ++round) {
        int cw = 0;
#pragma unroll
        for (int cc = 0; cc < CPW; ++cc) {
            int chunk = round * WIN + wave * CPW + cc;
            uint_t v = ids32[chunk * 64 + lane];
            int id0 = (int)(v & 0xFFFFu), id1 = (int)(v >> 16);
            int p0 = chunk * 128 + 2 * lane;
            u64 m0 = __ballot(id0 == k);
            u64 m1 = __ballot(id1 == k);
            int c0 = __popcll(m0);
            u64 lanem = (1ull << lane) - 1ull;
            if (id0 == k) list[wave][cw + __popcll(m0 & lanem)] = p0;
            if (id1 == k) list[wave][cw + c0 + __popcll(m1 & lanem)] = p0 + 1;
            cw += c0 + __popcll(m1);
        }
        if (lane == 0) lcnt[wave] = cw;
        cnttot += cw;
        __syncthreads();

        int off[CU_WAVES]; int T = 0;
#pragma unroll
        for (int j = 0; j < CU_WAVES; ++j) { off[j] = T; T += lcnt[j]; }

        for (int g0 = wave; g0 < T; g0 += CU_WAVES * 4) {
            int nb = 0; int pidx[4];
#pragma unroll
            for (int b = 0; b < 4; ++b) {
                int g = g0 + CU_WAVES * b;
                if (g < T) {
                    int j = 0;
#pragma unroll
                    for (int jj = 1; jj < CU_WAVES; ++jj) if (g >= off[jj]) j = jj;
                    pidx[nb++] = list[j][g - off[j]];
                }
            }
            float4 x[4][2];
#pragma unroll
            for (int b = 0; b < 4; ++b) if (b < nb) {
                const float4* r = (const float4*)(feats + (size_t)pidx[b] * D) + lane * 2;
                x[b][0] = r[0]; x[b][1] = r[1];
            }
#pragma unroll
            for (int b = 0; b < 4; ++b) if (b < nb) {
                f4add(a0, x[b][0]); f4add(a1, x[b][1]);
            }
        }
        __syncthreads();
    }

    part[wave][lane][0] = a0; part[wave][lane][1] = a1;
    if (lane == 0) pcnt_s[wave] = cnttot;
    __syncthreads();

    if (wave == 0) {
        float4 s0 = part[0][lane][0], s1 = part[0][lane][1];
        int c = pcnt_s[0];
#pragma unroll
        for (int w = 1; w < CU_WAVES; ++w) {
            f4add(s0, part[w][lane][0]); f4add(s1, part[w][lane][1]);
            c += pcnt_s[w];
        }

        float4* crow = (float4*)(cent + (size_t)k * D) + lane * 2;
        float4 c0, c1;
        if (c > 0) {
            float cf = (float)c;
            c0 = (float4){s0.x / cf, s0.y / cf, s0.z / cf, s0.w / cf};
            c1 = (float4){s1.x / cf, s1.y / cf, s1.z / cf, s1.w / cf};
        } else {
            c0 = crow[0]; c1 = crow[1];
        }
        crow[0] = c0; crow[1] = c1;

        ushort_t h; ushort4 hv, lv;
        h = f2bf(c0.x); hv.x = h; lv.x = f2bf(c0.x - bf2f(h));
        h = f2bf(c0.y); hv.y = h; lv.y = f2bf(c0.y - bf2f(h));
        h = f2bf(c0.z); hv.z = h; lv.z = f2bf(c0.z - bf2f(h));
        h = f2bf(c0.w); hv.w = h; lv.w = f2bf(c0.w - bf2f(h));
        ((ushort4*)(Bh + (size_t)k * D))[lane * 2] = hv;
        ((ushort4*)(Bl + (size_t)k * D))[lane * 2] = lv;
        h = f2bf(c1.x); hv.x = h; lv.x = f2bf(c1.x - bf2f(h));
        h = f2bf(c1.y); hv.y = h; lv.y = f2bf(c1.y - bf2f(h));
        h = f2bf(c1.z); hv.z = h; lv.z = f2bf(c1.z - bf2f(h));
        h = f2bf(c1.w); hv.w = h; lv.w = f2bf(c1.w - bf2f(h));
        ((ushort4*)(Bh + (size_t)k * D))[lane * 2 + 1] = hv;
        ((ushort4*)(Bl + (size_t)k * D))[lane * 2 + 1] = lv;

        float s = c0.x * c0.x + c0.y * c0.y + c0.z * c0.z + c0.w * c0.w
                + c1.x * c1.x + c1.y * c1.y + c1.z * c1.z + c1.w * c1.w;
        for (int o = 32; o > 0; o >>= 1) s += __shfl_xor(s, o, 64);
        if (lane == 0) csq[k] = s;
    }
}

// ---------- residual^2 segment sum, same scheme ----------
__global__ __launch_bounds__(512) void dist_gather(
    const float* __restrict__ feats, const float* __restrict__ cent,
    const uint_t* __restrict__ ids32, float* __restrict__ dists)
{
    __shared__ int list[CU_WAVES][CPW * 128];
    __shared__ int lcnt[CU_WAVES];
    __shared__ float4 part[CU_WAVES][64][2];

    const int tid = threadIdx.x;
    const int lane = tid & 63;
    const int wave = tid >> 6;
    const int k = (int)blockIdx.x;

    const float4* crow = (const float4*)(cent + (size_t)k * D) + lane * 2;
    const float4 c0 = crow[0], c1 = crow[1];

    float4 a0 = {0.f, 0.f, 0.f, 0.f}, a1 = {0.f, 0.f, 0.f, 0.f};

    for (int round = 0; round < ROUNDS; ++round) {
        int cw = 0;
#pragma unroll
        for (int cc = 0; cc < CPW; ++cc) {
            int chunk = round * WIN + wave * CPW + cc;
            uint_t v = ids32[chunk * 64 + lane];
            int id0 = (int)(v & 0xFFFFu), id1 = (int)(v >> 16);
            int p0 = chunk * 128 + 2 * lane;
            u64 m0 = __ballot(id0 == k);
            u64 m1 = __ballot(id1 == k);
            int cc0 = __popcll(m0);
            u64 lanem = (1ull << lane) - 1ull;
            if (id0 == k) list[wave][cw + __popcll(m0 & lanem)] = p0;
            if (id1 == k) list[wave][cw + cc0 + __popcll(m1 & lanem)] = p0 + 1;
            cw += cc0 + __popcll(m1);
        }
        if (lane == 0) lcnt[wave] = cw;
        __syncthreads();

        int off[CU_WAVES]; int T = 0;
#pragma unroll
        for (int j = 0; j < CU_WAVES; ++j) { off[j] = T; T += lcnt[j]; }

        for (int g0 = wave; g0 < T; g0 += CU_WAVES * 4) {
            int nb = 0; int pidx[4];
#pragma unroll
            for (int b = 0; b < 4; ++b) {
                int g = g0 + CU_WAVES * b;
                if (g < T) {
                    int j = 0;
#pragma unroll
                    for (int jj = 1; jj < CU_WAVES; ++jj) if (g >= off[jj]) j = jj;
                    pidx[nb++] = list[j][g - off[j]];
                }
            }
            float4 x[4][2];
#pragma unroll
            for (int b = 0; b < 4; ++b) if (b < nb) {
                const float4* r = (const float4*)(feats + (size_t)pidx[b] * D) + lane * 2;
                x[b][0] = r[0]; x[b][1] = r[1];
            }
#pragma unroll
            for (int b = 0; b < 4; ++b) if (b < nb) {
                float r;
                r = x[b][0].x - c0.x; a0.x += r * r;  r = x[b][0].y - c0.y; a0.y += r * r;
                r = x[b][0].z - c0.z; a0.z += r * r;  r = x[b][0].w - c0.w; a0.w += r * r;
                r = x[b][1].x - c1.x; a1.x += r * r;  r = x[b][1].y - c1.y; a1.y += r * r;
                r = x[b][1].z - c1.z; a1.z += r * r;  r = x[b][1].w - c1.w; a1.w += r * r;
            }
        }
        __syncthreads();
    }

    part[wave][lane][0] = a0; part[wave][lane][1] = a1;
    __syncthreads();
    if (wave == 0) {
        float4 s0 = part[0][lane][0], s1 = part[0][lane][1];
#pragma unroll
        for (int w = 1; w < CU_WAVES; ++w) { f4add(s0, part[w][lane][0]); f4add(s1, part[w][lane][1]); }
        float4* drow = (float4*)(dists + (size_t)k * D) + lane * 2;
        drow[0] = s0; drow[1] = s1;
    }
}

// ---------- loss ----------
__global__ void sump_kernel(const float* __restrict__ dists, double* __restrict__ S) {
    int idx = blockIdx.x * 256 + threadIdx.x;
    float v = expf(-(dists[idx] / CONCENTRATION));
    __shared__ float red[4];
    for (int off = 32; off > 0; off >>= 1) v += __shfl_down(v, off, 64);
    if ((threadIdx.x & 63) == 0) red[threadIdx.x >> 6] = v;
    __syncthreads();
    if (threadIdx.x == 0) atomicAdd(S, (double)(red[0] + red[1] + red[2] + red[3]));
}

__global__ void loss_kernel(const float* __restrict__ dists, const double* __restrict__ Sd,
                            double* __restrict__ acc2) {
    int idx = blockIdx.x * 256 + threadIdx.x;
    float S = (float)Sd[0];
    float dv = dists[idx];
    float p = expf(-(dv / CONCENTRATION));
    float q = p / S;
    float e = q * logf(q + EPS);
    float p2 = expf(-(dv / TEMPERATURE));
    float nl = logf(p2 + EPS);
    __shared__ float rede[4];
    __shared__ float redn[4];
    for (int off = 32; off > 0; off >>= 1) { e += __shfl_down(e, off, 64); nl += __shfl_down(nl, off, 64); }
    if ((threadIdx.x & 63) == 0) { rede[threadIdx.x >> 6] = e; redn[threadIdx.x >> 6] = nl; }
    __syncthreads();
    if (threadIdx.x == 0) {
        atomicAdd(&acc2[0], (double)(rede[0] + rede[1] + rede[2] + rede[3]));
        atomicAdd(&acc2[1], (double)(redn[0] + redn[1] + redn[2] + redn[3]));
    }
}

__global__ void finalize_kernel(const double* __restrict__ acc2, float* __restrict__ out) {
    double kd = (double)(K * D);
    double entropy = acc2[0] / kd;
    double nll = -(acc2[1] / kd);
    out[0] = (float)(entropy + nll);
}

extern "C" void kernel_launch(void* const* d_in, const int* in_sizes, int n_in,
                              void* d_out, int out_size, void* d_ws, size_t ws_size,
                              hipStream_t stream) {
    const float* feats = (const float*)d_in[0];
    float* out = (float*)d_out;

    ushort_t* Ah = (ushort_t*)d_ws;                  // N*D
    ushort_t* Al = Ah + (size_t)N * D;               // N*D
    ushort_t* Bh = Al + (size_t)N * D;               // K*D
    ushort_t* Bl = Bh + (size_t)K * D;               // K*D
    float* centroids = (float*)(Bl + (size_t)K * D); // K*D
    float* dists     = centroids + (size_t)K * D;    // K*D
    float* csq       = dists + (size_t)K * D;        // K
    u64*   best      = (u64*)(csq + K);              // N
    ushort_t* ids16  = (ushort_t*)(best + N);        // N
    double* scal     = (double*)(ids16 + N);         // 3 (16B-aligned)
    int*   panel_cnt = (int*)(scal + 4);             // N/BM = 128

    split_kernel<<<(N * D / 4) / 256, 256, 0, stream>>>(feats, Ah, Al, N * D / 4);
    hipMemcpyAsync(centroids, feats, (size_t)K * D * sizeof(float),
                   hipMemcpyDeviceToDevice, stream);
    rowsq_kernel<<<K / 4, 256, 0, stream>>>(feats, csq, K);
    hipMemsetAsync(best, 0xFF, (size_t)N * sizeof(u64), stream);
    hipMemsetAsync(panel_cnt, 0, (N / BM) * sizeof(int), stream);

    for (int it = 0; it < NUM_ITERS; ++it) {
        const ushort_t* bh = (it == 0) ? Ah : Bh;
        const ushort_t* bl = (it == 0) ? Al : Bl;
        assign_mfma<<<(N / BM) * (K / BN), 256, 0, stream>>>(
            Ah, Al, bh, bl, csq, best, ids16, panel_cnt);   // converts + resets best
        cluster_update<<<K, 512, 0, stream>>>(feats, (const uint_t*)ids16,
                                              centroids, Bh, Bl, csq);
    }
    assign_mfma<<<(N / BM) * (K / BN), 256, 0, stream>>>(
        Ah, Al, Bh, Bl, csq, best, ids16, panel_cnt);

    dist_gather<<<K, 512, 0, stream>>>(feats, centroids, (const uint_t*)ids16, dists);

    hipMemsetAsync(scal, 0, 3 * sizeof(double), stream);
    sump_kernel<<<(K * D) / 256, 256, 0, stream>>>(dists, &scal[0]);
    loss_kernel<<<(K * D) / 256, 256, 0, stream>>>(dists, &scal[0], &scal[1]);
    finalize_kernel<<<1, 1, 0, stream>>>(&scal[1], out);
}

// Round 12
// 1208.042 us; speedup vs baseline: 1.1605x; 1.1605x over previous
//
#include <hip/hip_runtime.h>
#include <math.h>

#define N 16384
#define D 512
#define K 1024
#define NUM_ITERS 10
#define TEMPERATURE 0.1f
#define CONCENTRATION 0.1f
#define EPS 1e-6f

typedef unsigned short ushort_t;
typedef unsigned int uint_t;
typedef unsigned long long u64;
typedef __attribute__((ext_vector_type(4))) float floatx4;
typedef __attribute__((ext_vector_type(8))) short shortx8;

#define BM 128
#define BN 128
#define BK 32

// ---------- bf16 split helpers ----------
__device__ inline ushort_t f2bf(float f) {
    unsigned b = __float_as_uint(f);
    b += 0x7FFFu + ((b >> 16) & 1u);   // RNE
    return (ushort_t)(b >> 16);
}
__device__ inline float bf2f(ushort_t h) { return __uint_as_float(((unsigned)h) << 16); }

__device__ inline unsigned ford(float f) {   // order-preserving float->uint
    unsigned b = __float_as_uint(f);
    return (b & 0x80000000u) ? ~b : (b | 0x80000000u);
}

__device__ inline void f4add(float4& a, const float4& b) {
    a.x += b.x; a.y += b.y; a.z += b.z; a.w += b.w;
}

__device__ inline void gld16(const void* g, void* l) {
    __builtin_amdgcn_global_load_lds(
        (const __attribute__((address_space(1))) void*)(uintptr_t)(g),
        (__attribute__((address_space(3))) void*)(uintptr_t)(l), 16, 0, 0);
}

// ---------- split fp32 -> (hi, lo) bf16 (A only, once) ----------
__global__ void split_kernel(const float* __restrict__ x, ushort_t* __restrict__ hi,
                             ushort_t* __restrict__ lo, int n4) {
    int i = blockIdx.x * 256 + threadIdx.x;
    if (i >= n4) return;
    float4 v = ((const float4*)x)[i];
    ushort_t h0 = f2bf(v.x), h1 = f2bf(v.y), h2 = f2bf(v.z), h3 = f2bf(v.w);
    ushort4 hv = {h0, h1, h2, h3};
    ushort4 lv = {f2bf(v.x - bf2f(h0)), f2bf(v.y - bf2f(h1)),
                  f2bf(v.z - bf2f(h2)), f2bf(v.w - bf2f(h3))};
    ((ushort4*)hi)[i] = hv;
    ((ushort4*)lo)[i] = lv;
}

// ---------- row sum-of-squares for INITIAL centroids only ----------
__global__ void rowsq_kernel(const float* __restrict__ x, float* __restrict__ out, int rows) {
    int row = blockIdx.x * 4 + (threadIdx.x >> 6);
    int lane = threadIdx.x & 63;
    if (row >= rows) return;
    const float* r = x + (size_t)row * D;
    float s = 0.f;
    for (int i = lane; i < D; i += 64) { float v = r[i]; s += v * v; }
    for (int off = 32; off > 0; off >>= 1) s += __shfl_down(s, off, 64);
    if (lane == 0) out[row] = s;
}

// ---------- MFMA assign (16x16x32, XOR-swizzled LDS — R9-verified, unchanged) ----------
__global__ __launch_bounds__(256) void assign_mfma(
    const ushort_t* __restrict__ Ah, const ushort_t* __restrict__ Al,
    const ushort_t* __restrict__ Bh, const ushort_t* __restrict__ Bl,
    const float* __restrict__ csq, u64* __restrict__ best)
{
    __shared__ __align__(16) ushort_t sAh[BM * BK];
    __shared__ __align__(16) ushort_t sAl[BM * BK];
    __shared__ __align__(16) ushort_t sBh[BN * BK];
    __shared__ __align__(16) ushort_t sBl[BN * BK];

    const int tid = threadIdx.x;
    const int lane = tid & 63;
    const int wave = tid >> 6;
    const int wr = wave >> 1, wc = wave & 1;     // 2x2 wave grid, wave tile 64x64
    const int quad = lane >> 4, l16 = lane & 15;

    const int q = (int)blockIdx.x;
    const int xid = q & 7;
    const int s = q >> 3;
    const int brow = ((s >> 3) << 3) + xid;
    const int bcol = s & 7;
    const int row0 = brow * BM, col0 = bcol * BN;

    floatx4 acc[4][4];
#pragma unroll
    for (int a = 0; a < 4; ++a)
#pragma unroll
        for (int b = 0; b < 4; ++b) acc[a][b] = (floatx4){0.f, 0.f, 0.f, 0.f};

    // staging: slot tid / tid+256; row = c>>2, kb = (c&3) ^ ((row>>1)&3)
    const int r_a = tid >> 2;
    const int dp = (((tid & 3) ^ ((r_a >> 1) & 3))) * 8;

    for (int d0 = 0; d0 < D; d0 += BK) {
        __syncthreads();
        {
            const size_t ga0 = (size_t)(row0 + r_a) * D + d0 + dp;
            const size_t ga1 = (size_t)(row0 + r_a + 64) * D + d0 + dp;
            const size_t gb0 = (size_t)(col0 + r_a) * D + d0 + dp;
            const size_t gb1 = (size_t)(col0 + r_a + 64) * D + d0 + dp;
            const int l0 = tid * 8;
            const int l1 = (tid + 256) * 8;
            gld16(Ah + ga0, sAh + l0); gld16(Ah + ga1, sAh + l1);
            gld16(Al + ga0, sAl + l0); gld16(Al + ga1, sAl + l1);
            gld16(Bh + gb0, sBh + l0); gld16(Bh + gb1, sBh + l1);
            gld16(Bl + gb0, sBl + l0); gld16(Bl + gb1, sBl + l1);
        }
        __syncthreads();

        shortx8 fah[4], fal[4], fbh[4], fbl[4];
#pragma unroll
        for (int t = 0; t < 4; ++t) {
            const int ar = wr * 64 + t * 16 + l16;
            const int bc = wc * 64 + t * 16 + l16;
            const int qa = (quad ^ ((ar >> 1) & 3)) * 8;
            const int qb = (quad ^ ((bc >> 1) & 3)) * 8;
            fah[t] = *(const shortx8*)&sAh[ar * BK + qa];
            fal[t] = *(const shortx8*)&sAl[ar * BK + qa];
            fbh[t] = *(const shortx8*)&sBh[bc * BK + qb];
            fbl[t] = *(const shortx8*)&sBl[bc * BK + qb];
        }
#pragma unroll
        for (int i = 0; i < 4; ++i)
#pragma unroll
            for (int j = 0; j < 4; ++j) {
                acc[i][j] = __builtin_amdgcn_mfma_f32_16x16x32_bf16(fah[i], fbh[j], acc[i][j], 0, 0, 0);
                acc[i][j] = __builtin_amdgcn_mfma_f32_16x16x32_bf16(fah[i], fbl[j], acc[i][j], 0, 0, 0);
                acc[i][j] = __builtin_amdgcn_mfma_f32_16x16x32_bf16(fal[i], fbh[j], acc[i][j], 0, 0, 0);
            }
    }

    float csqv[4];
#pragma unroll
    for (int j = 0; j < 4; ++j) csqv[j] = csq[col0 + wc * 64 + j * 16 + l16];

    const int k0 = col0 + wc * 64 + l16;
#pragma unroll
    for (int i = 0; i < 4; ++i) {
#pragma unroll
        for (int r = 0; r < 4; ++r) {
            float bv = csqv[0] - 2.0f * acc[i][0][r];
            int bk = k0;
#pragma unroll
            for (int j = 1; j < 4; ++j) {
                float v = csqv[j] - 2.0f * acc[i][j][r];
                int kk = k0 + j * 16;
                if (v < bv || (v == bv && kk < bk)) { bv = v; bk = kk; }
            }
#pragma unroll
            for (int m = 1; m < 16; m <<= 1) {
                float ov = __shfl_xor(bv, m, 64);
                int ok = __shfl_xor(bk, m, 64);
                if (ov < bv || (ov == bv && ok < bk)) { bv = ov; bk = ok; }
            }
            if (l16 == 0) {
                int p = row0 + wr * 64 + i * 16 + quad * 4 + r;
                u64 pk = ((u64)ford(bv) << 32) | (unsigned)bk;
                atomicMin(&best[p], pk);
            }
        }
    }
}

// ======== round-based gather-then-process segment reduce ========
// Scans `best` directly: the low u32 of each packed u64 IS the cluster id
// (k < 1024). Ping-pong: each block also resets its 16-entry slice of the
// OTHER best buffer for the next iteration (stream-ordered, no race).
#define CU_WAVES 8
#define CHUNKS64 (N / 64)          // 256 chunks of 64 points
#define ROUNDS 4
#define WIN (CHUNKS64 / ROUNDS)    // 64 chunks/round
#define CPW (WIN / CU_WAVES)       // 8 chunks per wave per round (cap 512 entries)

__global__ __launch_bounds__(512) void cluster_update(
    const float* __restrict__ feats, const u64* __restrict__ best,
    u64* __restrict__ best_other,
    float* __restrict__ cent, ushort_t* __restrict__ Bh, ushort_t* __restrict__ Bl,
    float* __restrict__ csq)
{
    __shared__ int list[CU_WAVES][CPW * 64];
    __shared__ int lcnt[CU_WAVES];
    __shared__ float4 part[CU_WAVES][64][2];
    __shared__ int pcnt_s[CU_WAVES];

    const int tid = threadIdx.x;
    const int lane = tid & 63;
    const int wave = tid >> 6;
    const int k = (int)blockIdx.x;
    const uint_t* idlo = (const uint_t*)best;   // id at index 2*p

    float4 a0 = {0.f, 0.f, 0.f, 0.f}, a1 = {0.f, 0.f, 0.f, 0.f};
    int cnttot = 0;

    for (int round = 0; round < ROUNDS; ++round) {
        int cw = 0;
#pragma unroll
        for (int cc = 0; cc < CPW; ++cc) {
            int chunk = round * WIN + wave * CPW + cc;
            int p = chunk * 64 + lane;
            uint_t id = idlo[2 * p];
            u64 m = __ballot(id == (uint_t)k);
            if (id == (uint_t)k)
                list[wave][cw + __popcll(m & ((1ull << lane) - 1ull))] = p;
            cw += __popcll(m);
        }
        if (lane == 0) lcnt[wave] = cw;
        cnttot += cw;
        __syncthreads();

        int off[CU_WAVES]; int T = 0;
#pragma unroll
        for (int j = 0; j < CU_WAVES; ++j) { off[j] = T; T += lcnt[j]; }

        for (int g0 = wave; g0 < T; g0 += CU_WAVES * 4) {
            int nb = 0; int pidx[4];
#pragma unroll
            for (int b = 0; b < 4; ++b) {
                int g = g0 + CU_WAVES * b;
                if (g < T) {
                    int j = 0;
#pragma unroll
                    for (int jj = 1; jj < CU_WAVES; ++jj) if (g >= off[jj]) j = jj;
                    pidx[nb++] = list[j][g - off[j]];
                }
            }
            float4 x[4][2];
#pragma unroll
            for (int b = 0; b < 4; ++b) if (b < nb) {
                const float4* r = (const float4*)(feats + (size_t)pidx[b] * D) + lane * 2;
                x[b][0] = r[0]; x[b][1] = r[1];
            }
#pragma unroll
            for (int b = 0; b < 4; ++b) if (b < nb) {
                f4add(a0, x[b][0]); f4add(a1, x[b][1]);
            }
        }
        __syncthreads();
    }

    part[wave][lane][0] = a0; part[wave][lane][1] = a1;
    if (lane == 0) pcnt_s[wave] = cnttot;
    __syncthreads();

    if (wave == 0) {
        float4 s0 = part[0][lane][0], s1 = part[0][lane][1];
        int c = pcnt_s[0];
#pragma unroll
        for (int w = 1; w < CU_WAVES; ++w) {
            f4add(s0, part[w][lane][0]); f4add(s1, part[w][lane][1]);
            c += pcnt_s[w];
        }

        float4* crow = (float4*)(cent + (size_t)k * D) + lane * 2;
        float4 c0, c1;
        if (c > 0) {
            float cf = (float)c;
            c0 = (float4){s0.x / cf, s0.y / cf, s0.z / cf, s0.w / cf};
            c1 = (float4){s1.x / cf, s1.y / cf, s1.z / cf, s1.w / cf};
        } else {
            c0 = crow[0]; c1 = crow[1];
        }
        crow[0] = c0; crow[1] = c1;

        ushort_t h; ushort4 hv, lv;
        h = f2bf(c0.x); hv.x = h; lv.x = f2bf(c0.x - bf2f(h));
        h = f2bf(c0.y); hv.y = h; lv.y = f2bf(c0.y - bf2f(h));
        h = f2bf(c0.z); hv.z = h; lv.z = f2bf(c0.z - bf2f(h));
        h = f2bf(c0.w); hv.w = h; lv.w = f2bf(c0.w - bf2f(h));
        ((ushort4*)(Bh + (size_t)k * D))[lane * 2] = hv;
        ((ushort4*)(Bl + (size_t)k * D))[lane * 2] = lv;
        h = f2bf(c1.x); hv.x = h; lv.x = f2bf(c1.x - bf2f(h));
        h = f2bf(c1.y); hv.y = h; lv.y = f2bf(c1.y - bf2f(h));
        h = f2bf(c1.z); hv.z = h; lv.z = f2bf(c1.z - bf2f(h));
        h = f2bf(c1.w); hv.w = h; lv.w = f2bf(c1.w - bf2f(h));
        ((ushort4*)(Bh + (size_t)k * D))[lane * 2 + 1] = hv;
        ((ushort4*)(Bl + (size_t)k * D))[lane * 2 + 1] = lv;

        float s = c0.x * c0.x + c0.y * c0.y + c0.z * c0.z + c0.w * c0.w
                + c1.x * c1.x + c1.y * c1.y + c1.z * c1.z + c1.w * c1.w;
        for (int o = 32; o > 0; o >>= 1) s += __shfl_xor(s, o, 64);
        if (lane == 0) csq[k] = s;
    }

    // reset our 16-entry slice of the OTHER buffer for the next assign
    if (tid < 16) best_other[k * 16 + tid] = ~0ull;
}

// ---------- residual^2 segment sum, same scan scheme ----------
__global__ __launch_bounds__(512) void dist_gather(
    const float* __restrict__ feats, const float* __restrict__ cent,
    const u64* __restrict__ best, float* __restrict__ dists)
{
    __shared__ int list[CU_WAVES][CPW * 64];
    __shared__ int lcnt[CU_WAVES];
    __shared__ float4 part[CU_WAVES][64][2];

    const int tid = threadIdx.x;
    const int lane = tid & 63;
    const int wave = tid >> 6;
    const int k = (int)blockIdx.x;
    const uint_t* idlo = (const uint_t*)best;

    const float4* crow = (const float4*)(cent + (size_t)k * D) + lane * 2;
    const float4 c0 = crow[0], c1 = crow[1];

    float4 a0 = {0.f, 0.f, 0.f, 0.f}, a1 = {0.f, 0.f, 0.f, 0.f};

    for (int round = 0; round < ROUNDS; ++round) {
        int cw = 0;
#pragma unroll
        for (int cc = 0; cc < CPW; ++cc) {
            int chunk = round * WIN + wave * CPW + cc;
            int p = chunk * 64 + lane;
            uint_t id = idlo[2 * p];
            u64 m = __ballot(id == (uint_t)k);
            if (id == (uint_t)k)
                list[wave][cw + __popcll(m & ((1ull << lane) - 1ull))] = p;
            cw += __popcll(m);
        }
        if (lane == 0) lcnt[wave] = cw;
        __syncthreads();

        int off[CU_WAVES]; int T = 0;
#pragma unroll
        for (int j = 0; j < CU_WAVES; ++j) { off[j] = T; T += lcnt[j]; }

        for (int g0 = wave; g0 < T; g0 += CU_WAVES * 4) {
            int nb = 0; int pidx[4];
#pragma unroll
            for (int b = 0; b < 4; ++b) {
                int g = g0 + CU_WAVES * b;
                if (g < T) {
                    int j = 0;
#pragma unroll
                    for (int jj = 1; jj < CU_WAVES; ++jj) if (g >= off[jj]) j = jj;
                    pidx[nb++] = list[j][g - off[j]];
                }
            }
            float4 x[4][2];
#pragma unroll
            for (int b = 0; b < 4; ++b) if (b < nb) {
                const float4* r = (const float4*)(feats + (size_t)pidx[b] * D) + lane * 2;
                x[b][0] = r[0]; x[b][1] = r[1];
            }
#pragma unroll
            for (int b = 0; b < 4; ++b) if (b < nb) {
                float r;
                r = x[b][0].x - c0.x; a0.x += r * r;  r = x[b][0].y - c0.y; a0.y += r * r;
                r = x[b][0].z - c0.z; a0.z += r * r;  r = x[b][0].w - c0.w; a0.w += r * r;
                r = x[b][1].x - c1.x; a1.x += r * r;  r = x[b][1].y - c1.y; a1.y += r * r;
                r = x[b][1].z - c1.z; a1.z += r * r;  r = x[b][1].w - c1.w; a1.w += r * r;
            }
        }
        __syncthreads();
    }

    part[wave][lane][0] = a0; part[wave][lane][1] = a1;
    __syncthreads();
    if (wave == 0) {
        float4 s0 = part[0][lane][0], s1 = part[0][lane][1];
#pragma unroll
        for (int w = 1; w < CU_WAVES; ++w) { f4add(s0, part[w][lane][0]); f4add(s1, part[w][lane][1]); }
        float4* drow = (float4*)(dists + (size_t)k * D) + lane * 2;
        drow[0] = s0; drow[1] = s1;
    }
}

// ---------- loss ----------
__global__ void sump_kernel(const float* __restrict__ dists, double* __restrict__ S) {
    int idx = blockIdx.x * 256 + threadIdx.x;
    float v = expf(-(dists[idx] / CONCENTRATION));
    __shared__ float red[4];
    for (int off = 32; off > 0; off >>= 1) v += __shfl_down(v, off, 64);
    if ((threadIdx.x & 63) == 0) red[threadIdx.x >> 6] = v;
    __syncthreads();
    if (threadIdx.x == 0) atomicAdd(S, (double)(red[0] + red[1] + red[2] + red[3]));
}

__global__ void loss_kernel(const float* __restrict__ dists, const double* __restrict__ Sd,
                            double* __restrict__ acc2) {
    int idx = blockIdx.x * 256 + threadIdx.x;
    float S = (float)Sd[0];
    float dv = dists[idx];
    float p = expf(-(dv / CONCENTRATION));
    float q = p / S;
    float e = q * logf(q + EPS);
    float p2 = expf(-(dv / TEMPERATURE));
    float nl = logf(p2 + EPS);
    __shared__ float rede[4];
    __shared__ float redn[4];
    for (int off = 32; off > 0; off >>= 1) { e += __shfl_down(e, off, 64); nl += __shfl_down(nl, off, 64); }
    if ((threadIdx.x & 63) == 0) { rede[threadIdx.x >> 6] = e; redn[threadIdx.x >> 6] = nl; }
    __syncthreads();
    if (threadIdx.x == 0) {
        atomicAdd(&acc2[0], (double)(rede[0] + rede[1] + rede[2] + rede[3]));
        atomicAdd(&acc2[1], (double)(redn[0] + redn[1] + redn[2] + redn[3]));
    }
}

__global__ void finalize_kernel(const double* __restrict__ acc2, float* __restrict__ out) {
    double kd = (double)(K * D);
    double entropy = acc2[0] / kd;
    double nll = -(acc2[1] / kd);
    out[0] = (float)(entropy + nll);
}

extern "C" void kernel_launch(void* const* d_in, const int* in_sizes, int n_in,
                              void* d_out, int out_size, void* d_ws, size_t ws_size,
                              hipStream_t stream) {
    const float* feats = (const float*)d_in[0];
    float* out = (float*)d_out;

    ushort_t* Ah = (ushort_t*)d_ws;                  // N*D
    ushort_t* Al = Ah + (size_t)N * D;               // N*D
    ushort_t* Bh = Al + (size_t)N * D;               // K*D
    ushort_t* Bl = Bh + (size_t)K * D;               // K*D
    float* centroids = (float*)(Bl + (size_t)K * D); // K*D
    float* dists     = centroids + (size_t)K * D;    // K*D
    float* csq       = dists + (size_t)K * D;        // K
    u64*   best0     = (u64*)(csq + K);              // N
    u64*   best1     = best0 + N;                    // N
    double* scal     = (double*)(best1 + N);         // 3

    split_kernel<<<(N * D / 4) / 256, 256, 0, stream>>>(feats, Ah, Al, N * D / 4);
    hipMemcpyAsync(centroids, feats, (size_t)K * D * sizeof(float),
                   hipMemcpyDeviceToDevice, stream);
    rowsq_kernel<<<K / 4, 256, 0, stream>>>(feats, csq, K);
    hipMemsetAsync(best0, 0xFF, 2 * (size_t)N * sizeof(u64), stream);

    for (int it = 0; it < NUM_ITERS; ++it) {
        u64* cur = (it & 1) ? best1 : best0;
        u64* oth = (it & 1) ? best0 : best1;
        const ushort_t* bh = (it == 0) ? Ah : Bh;
        const ushort_t* bl = (it == 0) ? Al : Bl;
        assign_mfma<<<(N / BM) * (K / BN), 256, 0, stream>>>(Ah, Al, bh, bl, csq, cur);
        cluster_update<<<K, 512, 0, stream>>>(feats, cur, oth, centroids, Bh, Bl, csq);
    }
    // final assign uses buffer (NUM_ITERS & 1) — reset by cluster_update(NUM_ITERS-1)
    u64* fin = (NUM_ITERS & 1) ? best1 : best0;
    assign_mfma<<<(N / BM) * (K / BN), 256, 0, stream>>>(Ah, Al, Bh, Bl, csq, fin);

    dist_gather<<<K, 512, 0, stream>>>(feats, centroids, fin, dists);

    hipMemsetAsync(scal, 0, 3 * sizeof(double), stream);
    sump_kernel<<<(K * D) / 256, 256, 0, stream>>>(dists, &scal[0]);
    loss_kernel<<<(K * D) / 256, 256, 0, stream>>>(dists, &scal[0], &scal[1]);
    finalize_kernel<<<1, 1, 0, stream>>>(&scal[1], out);
}

// Round 13
// 1004.938 us; speedup vs baseline: 1.3951x; 1.2021x over previous
//
#include <hip/hip_runtime.h>
#include <math.h>

#define N 16384
#define D 512
#define K 1024
#define NUM_ITERS 10
#define TEMPERATURE 0.1f
#define CONCENTRATION 0.1f
#define EPS 1e-6f

typedef unsigned short ushort_t;
typedef unsigned int uint_t;
typedef unsigned long long u64;
typedef __attribute__((ext_vector_type(4))) float floatx4;
typedef __attribute__((ext_vector_type(8))) short shortx8;

#define BM 128
#define BN 128
#define BK 32

// ---------- fp16 split helpers ----------
__device__ inline ushort_t f2h(float f) {
    _Float16 h = (_Float16)f;            // RNE
    return *(ushort_t*)&h;
}
__device__ inline float h2f(ushort_t u) {
    _Float16 h = *(_Float16*)&u;
    return (float)h;
}

__device__ inline unsigned ford(float f) {   // order-preserving float->uint
    unsigned b = __float_as_uint(f);
    return (b & 0x80000000u) ? ~b : (b | 0x80000000u);
}

__device__ inline void f4add(float4& a, const float4& b) {
    a.x += b.x; a.y += b.y; a.z += b.z; a.w += b.w;
}

__device__ inline void gld16(const void* g, void* l) {
    __builtin_amdgcn_global_load_lds(
        (const __attribute__((address_space(1))) void*)(uintptr_t)(g),
        (__attribute__((address_space(3))) void*)(uintptr_t)(l), 16, 0, 0);
}

// ---------- split fp32 -> (hi, lo) fp16 (A only, once) ----------
__global__ void split_kernel(const float* __restrict__ x, ushort_t* __restrict__ hi,
                             ushort_t* __restrict__ lo, int n4) {
    int i = blockIdx.x * 256 + threadIdx.x;
    if (i >= n4) return;
    float4 v = ((const float4*)x)[i];
    ushort_t h0 = f2h(v.x), h1 = f2h(v.y), h2 = f2h(v.z), h3 = f2h(v.w);
    ushort4 hv = {h0, h1, h2, h3};
    ushort4 lv = {f2h(v.x - h2f(h0)), f2h(v.y - h2f(h1)),
                  f2h(v.z - h2f(h2)), f2h(v.w - h2f(h3))};
    ((ushort4*)hi)[i] = hv;
    ((ushort4*)lo)[i] = lv;
}

// ---------- row sum-of-squares for INITIAL centroids only ----------
__global__ void rowsq_kernel(const float* __restrict__ x, float* __restrict__ out, int rows) {
    int row = blockIdx.x * 4 + (threadIdx.x >> 6);
    int lane = threadIdx.x & 63;
    if (row >= rows) return;
    const float* r = x + (size_t)row * D;
    float s = 0.f;
    for (int i = lane; i < D; i += 64) { float v = r[i]; s += v * v; }
    for (int off = 32; off > 0; off >>= 1) s += __shfl_down(s, off, 64);
    if (lane == 0) out[row] = s;
}

// ---------- MFMA assign (16x16x32 f16, 2-pass split-A, XOR-swizzled LDS) ----------
// dot = ah*bh + al*bh (A = two fp16, B = fp16-hi). Dropped a*bl term:
// err ~ 2^-12*sqrt(512)*|b| ~ 0.01 << typical argmin gap O(100).
// Staging/LDS layout identical to R9 (coalesced + XOR swizzle, 0 conflicts).
__global__ __launch_bounds__(256) void assign_mfma(
    const ushort_t* __restrict__ Ah, const ushort_t* __restrict__ Al,
    const ushort_t* __restrict__ Bh,
    const float* __restrict__ csq, u64* __restrict__ best)
{
    __shared__ __align__(16) ushort_t sAh[BM * BK];
    __shared__ __align__(16) ushort_t sAl[BM * BK];
    __shared__ __align__(16) ushort_t sBh[BN * BK];

    const int tid = threadIdx.x;
    const int lane = tid & 63;
    const int wave = tid >> 6;
    const int wr = wave >> 1, wc = wave & 1;     // 2x2 wave grid, wave tile 64x64
    const int quad = lane >> 4, l16 = lane & 15;

    const int q = (int)blockIdx.x;
    const int xid = q & 7;
    const int s = q >> 3;
    const int brow = ((s >> 3) << 3) + xid;
    const int bcol = s & 7;
    const int row0 = brow * BM, col0 = bcol * BN;

    floatx4 acc[4][4];
#pragma unroll
    for (int a = 0; a < 4; ++a)
#pragma unroll
        for (int b = 0; b < 4; ++b) acc[a][b] = (floatx4){0.f, 0.f, 0.f, 0.f};

    // staging: slot tid / tid+256; row = c>>2, kb = (c&3) ^ ((row>>1)&3)
    const int r_a = tid >> 2;
    const int dp = (((tid & 3) ^ ((r_a >> 1) & 3))) * 8;

    for (int d0 = 0; d0 < D; d0 += BK) {
        __syncthreads();
        {
            const size_t ga0 = (size_t)(row0 + r_a) * D + d0 + dp;
            const size_t ga1 = (size_t)(row0 + r_a + 64) * D + d0 + dp;
            const size_t gb0 = (size_t)(col0 + r_a) * D + d0 + dp;
            const size_t gb1 = (size_t)(col0 + r_a + 64) * D + d0 + dp;
            const int l0 = tid * 8;
            const int l1 = (tid + 256) * 8;
            gld16(Ah + ga0, sAh + l0); gld16(Ah + ga1, sAh + l1);
            gld16(Al + ga0, sAl + l0); gld16(Al + ga1, sAl + l1);
            gld16(Bh + gb0, sBh + l0); gld16(Bh + gb1, sBh + l1);
        }
        __syncthreads();

        shortx8 fah[4], fal[4], fbh[4];
#pragma unroll
        for (int t = 0; t < 4; ++t) {
            const int ar = wr * 64 + t * 16 + l16;
            const int bc = wc * 64 + t * 16 + l16;
            const int qa = (quad ^ ((ar >> 1) & 3)) * 8;
            const int qb = (quad ^ ((bc >> 1) & 3)) * 8;
            fah[t] = *(const shortx8*)&sAh[ar * BK + qa];
            fal[t] = *(const shortx8*)&sAl[ar * BK + qa];
            fbh[t] = *(const shortx8*)&sBh[bc * BK + qb];
        }
#pragma unroll
        for (int i = 0; i < 4; ++i)
#pragma unroll
            for (int j = 0; j < 4; ++j) {
                acc[i][j] = __builtin_amdgcn_mfma_f32_16x16x32_f16(fah[i], fbh[j], acc[i][j], 0, 0, 0);
                acc[i][j] = __builtin_amdgcn_mfma_f32_16x16x32_f16(fal[i], fbh[j], acc[i][j], 0, 0, 0);
            }
    }

    float csqv[4];
#pragma unroll
    for (int j = 0; j < 4; ++j) csqv[j] = csq[col0 + wc * 64 + j * 16 + l16];

    const int k0 = col0 + wc * 64 + l16;
#pragma unroll
    for (int i = 0; i < 4; ++i) {
#pragma unroll
        for (int r = 0; r < 4; ++r) {
            float bv = csqv[0] - 2.0f * acc[i][0][r];
            int bk = k0;
#pragma unroll
            for (int j = 1; j < 4; ++j) {
                float v = csqv[j] - 2.0f * acc[i][j][r];
                int kk = k0 + j * 16;
                if (v < bv || (v == bv && kk < bk)) { bv = v; bk = kk; }
            }
#pragma unroll
            for (int m = 1; m < 16; m <<= 1) {
                float ov = __shfl_xor(bv, m, 64);
                int ok = __shfl_xor(bk, m, 64);
                if (ov < bv || (ov == bv && ok < bk)) { bv = ov; bk = ok; }
            }
            if (l16 == 0) {
                int p = row0 + wr * 64 + i * 16 + quad * 4 + r;
                u64 pk = ((u64)ford(bv) << 32) | (unsigned)bk;
                atomicMin(&best[p], pk);
            }
        }
    }
}

// ---------- best(u64) -> packed u16 ids, fused reset of best to 0xFF ----------
__global__ void convert16_kernel(u64* __restrict__ best, ushort_t* __restrict__ ids) {
    int p = blockIdx.x * 256 + threadIdx.x;
    ids[p] = (ushort_t)(best[p] & 0xFFFFull);
    best[p] = ~0ull;
}

// ======== round-based gather-then-process segment reduce (u16 ids) ========
#define CU_WAVES 8
#define CHUNKS (N / 128)          // 128
#define ROUNDS 4
#define WIN (CHUNKS / ROUNDS)     // 32 chunks/round
#define CPW (WIN / CU_WAVES)      // 4 chunks per wave per round

__global__ __launch_bounds__(512) void cluster_update(
    const float* __restrict__ feats, const uint_t* __restrict__ ids32,
    float* __restrict__ cent, ushort_t* __restrict__ Bh,
    float* __restrict__ csq)
{
    __shared__ int list[CU_WAVES][CPW * 128];
    __shared__ int lcnt[CU_WAVES];
    __shared__ float4 part[CU_WAVES][64][2];
    __shared__ int pcnt_s[CU_WAVES];

    const int tid = threadIdx.x;
    const int lane = tid & 63;
    const int wave = tid >> 6;
    const int k = (int)blockIdx.x;

    float4 a0 = {0.f, 0.f, 0.f, 0.f}, a1 = {0.f, 0.f, 0.f, 0.f};
    int cnttot = 0;

    for (int round = 0; round < ROUNDS; ++round) {
        int cw = 0;
#pragma unroll
        for (int cc = 0; cc < CPW; ++cc) {
            int chunk = round * WIN + wave * CPW + cc;
            uint_t v = ids32[chunk * 64 + lane];
            int id0 = (int)(v & 0xFFFFu), id1 = (int)(v >> 16);
            int p0 = chunk * 128 + 2 * lane;
            u64 m0 = __ballot(id0 == k);
            u64 m1 = __ballot(id1 == k);
            int c0 = __popcll(m0);
            u64 lanem = (1ull << lane) - 1ull;
            if (id0 == k) list[wave][cw + __popcll(m0 & lanem)] = p0;
            if (id1 == k) list[wave][cw + c0 + __popcll(m1 & lanem)] = p0 + 1;
            cw += c0 + __popcll(m1);
        }
        if (lane == 0) lcnt[wave] = cw;
        cnttot += cw;
        __syncthreads();

        int off[CU_WAVES]; int T = 0;
#pragma unroll
        for (int j = 0; j < CU_WAVES; ++j) { off[j] = T; T += lcnt[j]; }

        for (int g0 = wave; g0 < T; g0 += CU_WAVES * 4) {
            int nb = 0; int pidx[4];
#pragma unroll
            for (int b = 0; b < 4; ++b) {
                int g = g0 + CU_WAVES * b;
                if (g < T) {
                    int j = 0;
#pragma unroll
                    for (int jj = 1; jj < CU_WAVES; ++jj) if (g >= off[jj]) j = jj;
                    pidx[nb++] = list[j][g - off[j]];
                }
            }
            float4 x[4][2];
#pragma unroll
            for (int b = 0; b < 4; ++b) if (b < nb) {
                const float4* r = (const float4*)(feats + (size_t)pidx[b] * D) + lane * 2;
                x[b][0] = r[0]; x[b][1] = r[1];
            }
#pragma unroll
            for (int b = 0; b < 4; ++b) if (b < nb) {
                f4add(a0, x[b][0]); f4add(a1, x[b][1]);
            }
        }
        __syncthreads();
    }

    part[wave][lane][0] = a0; part[wave][lane][1] = a1;
    if (lane == 0) pcnt_s[wave] = cnttot;
    __syncthreads();

    if (wave == 0) {
        float4 s0 = part[0][lane][0], s1 = part[0][lane][1];
        int c = pcnt_s[0];
#pragma unroll
        for (int w = 1; w < CU_WAVES; ++w) {
            f4add(s0, part[w][lane][0]); f4add(s1, part[w][lane][1]);
            c += pcnt_s[w];
        }

        float4* crow = (float4*)(cent + (size_t)k * D) + lane * 2;
        float4 c0, c1;
        if (c > 0) {
            float cf = (float)c;
            c0 = (float4){s0.x / cf, s0.y / cf, s0.z / cf, s0.w / cf};
            c1 = (float4){s1.x / cf, s1.y / cf, s1.z / cf, s1.w / cf};
        } else {
            c0 = crow[0]; c1 = crow[1];
        }
        crow[0] = c0; crow[1] = c1;

        ushort4 hv;
        hv.x = f2h(c0.x); hv.y = f2h(c0.y); hv.z = f2h(c0.z); hv.w = f2h(c0.w);
        ((ushort4*)(Bh + (size_t)k * D))[lane * 2] = hv;
        hv.x = f2h(c1.x); hv.y = f2h(c1.y); hv.z = f2h(c1.z); hv.w = f2h(c1.w);
        ((ushort4*)(Bh + (size_t)k * D))[lane * 2 + 1] = hv;

        float s = c0.x * c0.x + c0.y * c0.y + c0.z * c0.z + c0.w * c0.w
                + c1.x * c1.x + c1.y * c1.y + c1.z * c1.z + c1.w * c1.w;
        for (int o = 32; o > 0; o >>= 1) s += __shfl_xor(s, o, 64);
        if (lane == 0) csq[k] = s;
    }
}

// ---------- residual^2 segment sum, same scheme ----------
__global__ __launch_bounds__(512) void dist_gather(
    const float* __restrict__ feats, const float* __restrict__ cent,
    const uint_t* __restrict__ ids32, float* __restrict__ dists)
{
    __shared__ int list[CU_WAVES][CPW * 128];
    __shared__ int lcnt[CU_WAVES];
    __shared__ float4 part[CU_WAVES][64][2];

    const int tid = threadIdx.x;
    const int lane = tid & 63;
    const int wave = tid >> 6;
    const int k = (int)blockIdx.x;

    const float4* crow = (const float4*)(cent + (size_t)k * D) + lane * 2;
    const float4 c0 = crow[0], c1 = crow[1];

    float4 a0 = {0.f, 0.f, 0.f, 0.f}, a1 = {0.f, 0.f, 0.f, 0.f};

    for (int round = 0; round < ROUNDS; ++round) {
        int cw = 0;
#pragma unroll
        for (int cc = 0; cc < CPW; ++cc) {
            int chunk = round * WIN + wave * CPW + cc;
            uint_t v = ids32[chunk * 64 + lane];
            int id0 = (int)(v & 0xFFFFu), id1 = (int)(v >> 16);
            int p0 = chunk * 128 + 2 * lane;
            u64 m0 = __ballot(id0 == k);
            u64 m1 = __ballot(id1 == k);
            int cc0 = __popcll(m0);
            u64 lanem = (1ull << lane) - 1ull;
            if (id0 == k) list[wave][cw + __popcll(m0 & lanem)] = p0;
            if (id1 == k) list[wave][cw + cc0 + __popcll(m1 & lanem)] = p0 + 1;
            cw += cc0 + __popcll(m1);
        }
        if (lane == 0) lcnt[wave] = cw;
        __syncthreads();

        int off[CU_WAVES]; int T = 0;
#pragma unroll
        for (int j = 0; j < CU_WAVES; ++j) { off[j] = T; T += lcnt[j]; }

        for (int g0 = wave; g0 < T; g0 += CU_WAVES * 4) {
            int nb = 0; int pidx[4];
#pragma unroll
            for (int b = 0; b < 4; ++b) {
                int g = g0 + CU_WAVES * b;
                if (g < T) {
                    int j = 0;
#pragma unroll
                    for (int jj = 1; jj < CU_WAVES; ++jj) if (g >= off[jj]) j = jj;
                    pidx[nb++] = list[j][g - off[j]];
                }
            }
            float4 x[4][2];
#pragma unroll
            for (int b = 0; b < 4; ++b) if (b < nb) {
                const float4* r = (const float4*)(feats + (size_t)pidx[b] * D) + lane * 2;
                x[b][0] = r[0]; x[b][1] = r[1];
            }
#pragma unroll
            for (int b = 0; b < 4; ++b) if (b < nb) {
                float r;
                r = x[b][0].x - c0.x; a0.x += r * r;  r = x[b][0].y - c0.y; a0.y += r * r;
                r = x[b][0].z - c0.z; a0.z += r * r;  r = x[b][0].w - c0.w; a0.w += r * r;
                r = x[b][1].x - c1.x; a1.x += r * r;  r = x[b][1].y - c1.y; a1.y += r * r;
                r = x[b][1].z - c1.z; a1.z += r * r;  r = x[b][1].w - c1.w; a1.w += r * r;
            }
        }
        __syncthreads();
    }

    part[wave][lane][0] = a0; part[wave][lane][1] = a1;
    __syncthreads();
    if (wave == 0) {
        float4 s0 = part[0][lane][0], s1 = part[0][lane][1];
#pragma unroll
        for (int w = 1; w < CU_WAVES; ++w) { f4add(s0, part[w][lane][0]); f4add(s1, part[w][lane][1]); }
        float4* drow = (float4*)(dists + (size_t)k * D) + lane * 2;
        drow[0] = s0; drow[1] = s1;
    }
}

// ---------- loss ----------
__global__ void sump_kernel(const float* __restrict__ dists, double* __restrict__ S) {
    int idx = blockIdx.x * 256 + threadIdx.x;
    float v = expf(-(dists[idx] / CONCENTRATION));
    __shared__ float red[4];
    for (int off = 32; off > 0; off >>= 1) v += __shfl_down(v, off, 64);
    if ((threadIdx.x & 63) == 0) red[threadIdx.x >> 6] = v;
    __syncthreads();
    if (threadIdx.x == 0) atomicAdd(S, (double)(red[0] + red[1] + red[2] + red[3]));
}

__global__ void loss_kernel(const float* __restrict__ dists, const double* __restrict__ Sd,
                            double* __restrict__ acc2) {
    int idx = blockIdx.x * 256 + threadIdx.x;
    float S = (float)Sd[0];
    float dv = dists[idx];
    float p = expf(-(dv / CONCENTRATION));
    float q = p / S;
    float e = q * logf(q + EPS);
    float p2 = expf(-(dv / TEMPERATURE));
    float nl = logf(p2 + EPS);
    __shared__ float rede[4];
    __shared__ float redn[4];
    for (int off = 32; off > 0; off >>= 1) { e += __shfl_down(e, off, 64); nl += __shfl_down(nl, off, 64); }
    if ((threadIdx.x & 63) == 0) { rede[threadIdx.x >> 6] = e; redn[threadIdx.x >> 6] = nl; }
    __syncthreads();
    if (threadIdx.x == 0) {
        atomicAdd(&acc2[0], (double)(rede[0] + rede[1] + rede[2] + rede[3]));
        atomicAdd(&acc2[1], (double)(redn[0] + redn[1] + redn[2] + redn[3]));
    }
}

__global__ void finalize_kernel(const double* __restrict__ acc2, float* __restrict__ out) {
    double kd = (double)(K * D);
    double entropy = acc2[0] / kd;
    double nll = -(acc2[1] / kd);
    out[0] = (float)(entropy + nll);
}

extern "C" void kernel_launch(void* const* d_in, const int* in_sizes, int n_in,
                              void* d_out, int out_size, void* d_ws, size_t ws_size,
                              hipStream_t stream) {
    const float* feats = (const float*)d_in[0];
    float* out = (float*)d_out;

    ushort_t* Ah = (ushort_t*)d_ws;                  // N*D
    ushort_t* Al = Ah + (size_t)N * D;               // N*D
    ushort_t* Bh = Al + (size_t)N * D;               // K*D
    float* centroids = (float*)(Bh + (size_t)K * D); // K*D
    float* dists     = centroids + (size_t)K * D;    // K*D
    float* csq       = dists + (size_t)K * D;        // K
    u64*   best      = (u64*)(csq + K);              // N
    ushort_t* ids16  = (ushort_t*)(best + N);        // N
    double* scal     = (double*)(ids16 + N);         // 3

    split_kernel<<<(N * D / 4) / 256, 256, 0, stream>>>(feats, Ah, Al, N * D / 4);
    hipMemcpyAsync(centroids, feats, (size_t)K * D * sizeof(float),
                   hipMemcpyDeviceToDevice, stream);
    rowsq_kernel<<<K / 4, 256, 0, stream>>>(feats, csq, K);
    hipMemsetAsync(best, 0xFF, (size_t)N * sizeof(u64), stream);

    for (int it = 0; it < NUM_ITERS; ++it) {
        // iteration 0: B-hi = first K rows of A-hi (init centroids = feats[:K])
        const ushort_t* bh = (it == 0) ? Ah : Bh;
        assign_mfma<<<(N / BM) * (K / BN), 256, 0, stream>>>(Ah, Al, bh, csq, best);
        convert16_kernel<<<N / 256, 256, 0, stream>>>(best, ids16);   // also resets best
        cluster_update<<<K, 512, 0, stream>>>(feats, (const uint_t*)ids16,
                                              centroids, Bh, csq);
    }
    assign_mfma<<<(N / BM) * (K / BN), 256, 0, stream>>>(Ah, Al, Bh, csq, best);
    convert16_kernel<<<N / 256, 256, 0, stream>>>(best, ids16);

    dist_gather<<<K, 512, 0, stream>>>(feats, centroids, (const uint_t*)ids16, dists);

    hipMemsetAsync(scal, 0, 3 * sizeof(double), stream);
    sump_kernel<<<(K * D) / 256, 256, 0, stream>>>(dists, &scal[0]);
    loss_kernel<<<(K * D) / 256, 256, 0, stream>>>(dists, &scal[0], &scal[1]);
    finalize_kernel<<<1, 1, 0, stream>>>(&scal[1], out);
}

// Round 14
// 884.885 us; speedup vs baseline: 1.5844x; 1.1357x over previous
//
#include <hip/hip_runtime.h>
#include <math.h>

#define N 16384
#define D 512
#define K 1024
#define NUM_ITERS 10
#define TEMPERATURE 0.1f
#define CONCENTRATION 0.1f
#define EPS 1e-6f

typedef unsigned short ushort_t;
typedef unsigned int uint_t;
typedef unsigned long long u64;
typedef __attribute__((ext_vector_type(4))) float floatx4;
typedef __attribute__((ext_vector_type(8))) short shortx8;

#define BM 128
#define BN 128
#define BK 32

// ---------- fp16 helpers ----------
__device__ inline ushort_t f2h(float f) {
    _Float16 h = (_Float16)f;            // RNE
    return *(ushort_t*)&h;
}

__device__ inline unsigned ford(float f) {   // order-preserving float->uint
    unsigned b = __float_as_uint(f);
    return (b & 0x80000000u) ? ~b : (b | 0x80000000u);
}

__device__ inline void f4add(float4& a, const float4& b) {
    a.x += b.x; a.y += b.y; a.z += b.z; a.w += b.w;
}

__device__ inline void gld16(const void* g, void* l) {
    __builtin_amdgcn_global_load_lds(
        (const __attribute__((address_space(1))) void*)(uintptr_t)(g),
        (__attribute__((address_space(3))) void*)(uintptr_t)(l), 16, 0, 0);
}

// ---------- cast fp32 -> fp16 (A, once) + init best ----------
__global__ void split_kernel(const float* __restrict__ x, ushort_t* __restrict__ hi,
                             u64* __restrict__ best, int n4) {
    int i = blockIdx.x * 256 + threadIdx.x;
    if (i >= n4) return;
    float4 v = ((const float4*)x)[i];
    ushort4 hv = {f2h(v.x), f2h(v.y), f2h(v.z), f2h(v.w)};
    ((ushort4*)hi)[i] = hv;
    if (i < N) best[i] = ~0ull;
}

// ---------- row sum-of-squares for INITIAL centroids only ----------
__global__ void rowsq_kernel(const float* __restrict__ x, float* __restrict__ out, int rows) {
    int row = blockIdx.x * 4 + (threadIdx.x >> 6);
    int lane = threadIdx.x & 63;
    if (row >= rows) return;
    const float* r = x + (size_t)row * D;
    float s = 0.f;
    for (int i = lane; i < D; i += 64) { float v = r[i]; s += v * v; }
    for (int off = 32; off > 0; off >>= 1) s += __shfl_down(s, off, 64);
    if (lane == 0) out[row] = s;
}

// ---------- MFMA assign (16x16x32 f16, single-pass, XOR-swizzled LDS) ----------
// dot = ah*bh. Error ~ eps_a*b + a*eps_b ~ 0.009 rms on dot (0.019 on dist),
// << argmin gaps (R13's 2-pass at 0.007 rms had ZERO flips / absmax 0.0).
// Staging/LDS layout identical to R9/R13 (coalesced + XOR swizzle, 0 conflicts).
__global__ __launch_bounds__(256) void assign_mfma(
    const ushort_t* __restrict__ Ah, const ushort_t* __restrict__ Bh,
    const float* __restrict__ csq, u64* __restrict__ best)
{
    __shared__ __align__(16) ushort_t sAh[BM * BK];
    __shared__ __align__(16) ushort_t sBh[BN * BK];

    const int tid = threadIdx.x;
    const int lane = tid & 63;
    const int wave = tid >> 6;
    const int wr = wave >> 1, wc = wave & 1;     // 2x2 wave grid, wave tile 64x64
    const int quad = lane >> 4, l16 = lane & 15;

    const int q = (int)blockIdx.x;
    const int xid = q & 7;
    const int s = q >> 3;
    const int brow = ((s >> 3) << 3) + xid;
    const int bcol = s & 7;
    const int row0 = brow * BM, col0 = bcol * BN;

    floatx4 acc[4][4];
#pragma unroll
    for (int a = 0; a < 4; ++a)
#pragma unroll
        for (int b = 0; b < 4; ++b) acc[a][b] = (floatx4){0.f, 0.f, 0.f, 0.f};

    // staging: slot tid / tid+256; row = c>>2, kb = (c&3) ^ ((row>>1)&3)
    const int r_a = tid >> 2;
    const int dp = (((tid & 3) ^ ((r_a >> 1) & 3))) * 8;

    for (int d0 = 0; d0 < D; d0 += BK) {
        __syncthreads();
        {
            const size_t ga0 = (size_t)(row0 + r_a) * D + d0 + dp;
            const size_t ga1 = (size_t)(row0 + r_a + 64) * D + d0 + dp;
            const size_t gb0 = (size_t)(col0 + r_a) * D + d0 + dp;
            const size_t gb1 = (size_t)(col0 + r_a + 64) * D + d0 + dp;
            const int l0 = tid * 8;
            const int l1 = (tid + 256) * 8;
            gld16(Ah + ga0, sAh + l0); gld16(Ah + ga1, sAh + l1);
            gld16(Bh + gb0, sBh + l0); gld16(Bh + gb1, sBh + l1);
        }
        __syncthreads();

        shortx8 fah[4], fbh[4];
#pragma unroll
        for (int t = 0; t < 4; ++t) {
            const int ar = wr * 64 + t * 16 + l16;
            const int bc = wc * 64 + t * 16 + l16;
            const int qa = (quad ^ ((ar >> 1) & 3)) * 8;
            const int qb = (quad ^ ((bc >> 1) & 3)) * 8;
            fah[t] = *(const shortx8*)&sAh[ar * BK + qa];
            fbh[t] = *(const shortx8*)&sBh[bc * BK + qb];
        }
#pragma unroll
        for (int i = 0; i < 4; ++i)
#pragma unroll
            for (int j = 0; j < 4; ++j)
                acc[i][j] = __builtin_amdgcn_mfma_f32_16x16x32_f16(fah[i], fbh[j], acc[i][j], 0, 0, 0);
    }

    float csqv[4];
#pragma unroll
    for (int j = 0; j < 4; ++j) csqv[j] = csq[col0 + wc * 64 + j * 16 + l16];

    const int k0 = col0 + wc * 64 + l16;
#pragma unroll
    for (int i = 0; i < 4; ++i) {
#pragma unroll
        for (int r = 0; r < 4; ++r) {
            float bv = csqv[0] - 2.0f * acc[i][0][r];
            int bk = k0;
#pragma unroll
            for (int j = 1; j < 4; ++j) {
                float v = csqv[j] - 2.0f * acc[i][j][r];
                int kk = k0 + j * 16;
                if (v < bv || (v == bv && kk < bk)) { bv = v; bk = kk; }
            }
#pragma unroll
            for (int m = 1; m < 16; m <<= 1) {
                float ov = __shfl_xor(bv, m, 64);
                int ok = __shfl_xor(bk, m, 64);
                if (ov < bv || (ov == bv && ok < bk)) { bv = ov; bk = ok; }
            }
            if (l16 == 0) {
                int p = row0 + wr * 64 + i * 16 + quad * 4 + r;
                u64 pk = ((u64)ford(bv) << 32) | (unsigned)bk;
                atomicMin(&best[p], pk);
            }
        }
    }
}

// ---------- best(u64) -> packed u16 ids, fused reset of best to 0xFF ----------
__global__ void convert16_kernel(u64* __restrict__ best, ushort_t* __restrict__ ids) {
    int p = blockIdx.x * 256 + threadIdx.x;
    ids[p] = (ushort_t)(best[p] & 0xFFFFull);
    best[p] = ~0ull;
}

// ======== round-based gather-then-process segment reduce (u16 ids) ========
#define CU_WAVES 8
#define CHUNKS (N / 128)          // 128
#define ROUNDS 4
#define WIN (CHUNKS / ROUNDS)     // 32 chunks/round
#define CPW (WIN / CU_WAVES)      // 4 chunks per wave per round

__global__ __launch_bounds__(512) void cluster_update(
    const float* __restrict__ feats, const uint_t* __restrict__ ids32,
    float* __restrict__ cent, ushort_t* __restrict__ Bh,
    float* __restrict__ csq)
{
    __shared__ int list[CU_WAVES][CPW * 128];
    __shared__ int lcnt[CU_WAVES];
    __shared__ float4 part[CU_WAVES][64][2];
    __shared__ int pcnt_s[CU_WAVES];

    const int tid = threadIdx.x;
    const int lane = tid & 63;
    const int wave = tid >> 6;
    const int k = (int)blockIdx.x;

    float4 a0 = {0.f, 0.f, 0.f, 0.f}, a1 = {0.f, 0.f, 0.f, 0.f};
    int cnttot = 0;

    for (int round = 0; round < ROUNDS; ++round) {
        int cw = 0;
#pragma unroll
        for (int cc = 0; cc < CPW; ++cc) {
            int chunk = round * WIN + wave * CPW + cc;
            uint_t v = ids32[chunk * 64 + lane];
            int id0 = (int)(v & 0xFFFFu), id1 = (int)(v >> 16);
            int p0 = chunk * 128 + 2 * lane;
            u64 m0 = __ballot(id0 == k);
            u64 m1 = __ballot(id1 == k);
            int c0 = __popcll(m0);
            u64 lanem = (1ull << lane) - 1ull;
            if (id0 == k) list[wave][cw + __popcll(m0 & lanem)] = p0;
            if (id1 == k) list[wave][cw + c0 + __popcll(m1 & lanem)] = p0 + 1;
            cw += c0 + __popcll(m1);
        }
        if (lane == 0) lcnt[wave] = cw;
        cnttot += cw;
        __syncthreads();

        int off[CU_WAVES]; int T = 0;
#pragma unroll
        for (int j = 0; j < CU_WAVES; ++j) { off[j] = T; T += lcnt[j]; }

        for (int g0 = wave; g0 < T; g0 += CU_WAVES * 4) {
            int nb = 0; int pidx[4];
#pragma unroll
            for (int b = 0; b < 4; ++b) {
                int g = g0 + CU_WAVES * b;
                if (g < T) {
                    int j = 0;
#pragma unroll
                    for (int jj = 1; jj < CU_WAVES; ++jj) if (g >= off[jj]) j = jj;
                    pidx[nb++] = list[j][g - off[j]];
                }
            }
            float4 x[4][2];
#pragma unroll
            for (int b = 0; b < 4; ++b) if (b < nb) {
                const float4* r = (const float4*)(feats + (size_t)pidx[b] * D) + lane * 2;
                x[b][0] = r[0]; x[b][1] = r[1];
            }
#pragma unroll
            for (int b = 0; b < 4; ++b) if (b < nb) {
                f4add(a0, x[b][0]); f4add(a1, x[b][1]);
            }
        }
        __syncthreads();
    }

    part[wave][lane][0] = a0; part[wave][lane][1] = a1;
    if (lane == 0) pcnt_s[wave] = cnttot;
    __syncthreads();

    if (wave == 0) {
        float4 s0 = part[0][lane][0], s1 = part[0][lane][1];
        int c = pcnt_s[0];
#pragma unroll
        for (int w = 1; w < CU_WAVES; ++w) {
            f4add(s0, part[w][lane][0]); f4add(s1, part[w][lane][1]);
            c += pcnt_s[w];
        }

        float4* crow = (float4*)(cent + (size_t)k * D) + lane * 2;
        float4 c0, c1;
        if (c > 0) {
            float cf = (float)c;
            c0 = (float4){s0.x / cf, s0.y / cf, s0.z / cf, s0.w / cf};
            c1 = (float4){s1.x / cf, s1.y / cf, s1.z / cf, s1.w / cf};
        } else {
            c0 = crow[0]; c1 = crow[1];
        }
        crow[0] = c0; crow[1] = c1;

        ushort4 hv;
        hv.x = f2h(c0.x); hv.y = f2h(c0.y); hv.z = f2h(c0.z); hv.w = f2h(c0.w);
        ((ushort4*)(Bh + (size_t)k * D))[lane * 2] = hv;
        hv.x = f2h(c1.x); hv.y = f2h(c1.y); hv.z = f2h(c1.z); hv.w = f2h(c1.w);
        ((ushort4*)(Bh + (size_t)k * D))[lane * 2 + 1] = hv;

        float s = c0.x * c0.x + c0.y * c0.y + c0.z * c0.z + c0.w * c0.w
                + c1.x * c1.x + c1.y * c1.y + c1.z * c1.z + c1.w * c1.w;
        for (int o = 32; o > 0; o >>= 1) s += __shfl_xor(s, o, 64);
        if (lane == 0) csq[k] = s;
    }
}

// ---------- residual^2 segment sum, same scheme ----------
__global__ __launch_bounds__(512) void dist_gather(
    const float* __restrict__ feats, const float* __restrict__ cent,
    const uint_t* __restrict__ ids32, float* __restrict__ dists)
{
    __shared__ int list[CU_WAVES][CPW * 128];
    __shared__ int lcnt[CU_WAVES];
    __shared__ float4 part[CU_WAVES][64][2];

    const int tid = threadIdx.x;
    const int lane = tid & 63;
    const int wave = tid >> 6;
    const int k = (int)blockIdx.x;

    const float4* crow = (const float4*)(cent + (size_t)k * D) + lane * 2;
    const float4 c0 = crow[0], c1 = crow[1];

    float4 a0 = {0.f, 0.f, 0.f, 0.f}, a1 = {0.f, 0.f, 0.f, 0.f};

    for (int round = 0; round < ROUNDS; ++round) {
        int cw = 0;
#pragma unroll
        for (int cc = 0; cc < CPW; ++cc) {
            int chunk = round * WIN + wave * CPW + cc;
            uint_t v = ids32[chunk * 64 + lane];
            int id0 = (int)(v & 0xFFFFu), id1 = (int)(v >> 16);
            int p0 = chunk * 128 + 2 * lane;
            u64 m0 = __ballot(id0 == k);
            u64 m1 = __ballot(id1 == k);
            int cc0 = __popcll(m0);
            u64 lanem = (1ull << lane) - 1ull;
            if (id0 == k) list[wave][cw + __popcll(m0 & lanem)] = p0;
            if (id1 == k) list[wave][cw + cc0 + __popcll(m1 & lanem)] = p0 + 1;
            cw += cc0 + __popcll(m1);
        }
        if (lane == 0) lcnt[wave] = cw;
        __syncthreads();

        int off[CU_WAVES]; int T = 0;
#pragma unroll
        for (int j = 0; j < CU_WAVES; ++j) { off[j] = T; T += lcnt[j]; }

        for (int g0 = wave; g0 < T; g0 += CU_WAVES * 4) {
            int nb = 0; int pidx[4];
#pragma unroll
            for (int b = 0; b < 4; ++b) {
                int g = g0 + CU_WAVES * b;
                if (g < T) {
                    int j = 0;
#pragma unroll
                    for (int jj = 1; jj < CU_WAVES; ++jj) if (g >= off[jj]) j = jj;
                    pidx[nb++] = list[j][g - off[j]];
                }
            }
            float4 x[4][2];
#pragma unroll
            for (int b = 0; b < 4; ++b) if (b < nb) {
                const float4* r = (const float4*)(feats + (size_t)pidx[b] * D) + lane * 2;
                x[b][0] = r[0]; x[b][1] = r[1];
            }
#pragma unroll
            for (int b = 0; b < 4; ++b) if (b < nb) {
                float r;
                r = x[b][0].x - c0.x; a0.x += r * r;  r = x[b][0].y - c0.y; a0.y += r * r;
                r = x[b][0].z - c0.z; a0.z += r * r;  r = x[b][0].w - c0.w; a0.w += r * r;
                r = x[b][1].x - c1.x; a1.x += r * r;  r = x[b][1].y - c1.y; a1.y += r * r;
                r = x[b][1].z - c1.z; a1.z += r * r;  r = x[b][1].w - c1.w; a1.w += r * r;
            }
        }
        __syncthreads();
    }

    part[wave][lane][0] = a0; part[wave][lane][1] = a1;
    __syncthreads();
    if (wave == 0) {
        float4 s0 = part[0][lane][0], s1 = part[0][lane][1];
#pragma unroll
        for (int w = 1; w < CU_WAVES; ++w) { f4add(s0, part[w][lane][0]); f4add(s1, part[w][lane][1]); }
        float4* drow = (float4*)(dists + (size_t)k * D) + lane * 2;
        drow[0] = s0; drow[1] = s1;
    }
}

// ---------- loss ----------
__global__ void sump_kernel(const float* __restrict__ dists, double* __restrict__ S) {
    int idx = blockIdx.x * 256 + threadIdx.x;
    float v = expf(-(dists[idx] / CONCENTRATION));
    __shared__ float red[4];
    for (int off = 32; off > 0; off >>= 1) v += __shfl_down(v, off, 64);
    if ((threadIdx.x & 63) == 0) red[threadIdx.x >> 6] = v;
    __syncthreads();
    if (threadIdx.x == 0) atomicAdd(S, (double)(red[0] + red[1] + red[2] + red[3]));
}

__global__ void loss_kernel(const float* __restrict__ dists, const double* __restrict__ Sd,
                            double* __restrict__ acc2) {
    int idx = blockIdx.x * 256 + threadIdx.x;
    float S = (float)Sd[0];
    float dv = dists[idx];
    float p = expf(-(dv / CONCENTRATION));
    float q = p / S;
    float e = q * logf(q + EPS);
    float p2 = expf(-(dv / TEMPERATURE));
    float nl = logf(p2 + EPS);
    __shared__ float rede[4];
    __shared__ float redn[4];
    for (int off = 32; off > 0; off >>= 1) { e += __shfl_down(e, off, 64); nl += __shfl_down(nl, off, 64); }
    if ((threadIdx.x & 63) == 0) { rede[threadIdx.x >> 6] = e; redn[threadIdx.x >> 6] = nl; }
    __syncthreads();
    if (threadIdx.x == 0) {
        atomicAdd(&acc2[0], (double)(rede[0] + rede[1] + rede[2] + rede[3]));
        atomicAdd(&acc2[1], (double)(redn[0] + redn[1] + redn[2] + redn[3]));
    }
}

__global__ void finalize_kernel(const double* __restrict__ acc2, float* __restrict__ out) {
    double kd = (double)(K * D);
    double entropy = acc2[0] / kd;
    double nll = -(acc2[1] / kd);
    out[0] = (float)(entropy + nll);
}

extern "C" void kernel_launch(void* const* d_in, const int* in_sizes, int n_in,
                              void* d_out, int out_size, void* d_ws, size_t ws_size,
                              hipStream_t stream) {
    const float* feats = (const float*)d_in[0];
    float* out = (float*)d_out;

    ushort_t* Ah = (ushort_t*)d_ws;                  // N*D
    ushort_t* Bh = Ah + (size_t)N * D;               // K*D
    float* centroids = (float*)(Bh + (size_t)K * D); // K*D
    float* dists     = centroids + (size_t)K * D;    // K*D
    float* csq       = dists + (size_t)K * D;        // K
    u64*   best      = (u64*)(csq + K);              // N
    ushort_t* ids16  = (ushort_t*)(best + N);        // N
    double* scal     = (double*)(ids16 + N);         // 3

    split_kernel<<<(N * D / 4) / 256, 256, 0, stream>>>(feats, Ah, best, N * D / 4);
    hipMemcpyAsync(centroids, feats, (size_t)K * D * sizeof(float),
                   hipMemcpyDeviceToDevice, stream);
    rowsq_kernel<<<K / 4, 256, 0, stream>>>(feats, csq, K);

    for (int it = 0; it < NUM_ITERS; ++it) {
        // iteration 0: B = first K rows of A (init centroids = feats[:K])
        const ushort_t* bh = (it == 0) ? Ah : Bh;
        assign_mfma<<<(N / BM) * (K / BN), 256, 0, stream>>>(Ah, bh, csq, best);
        convert16_kernel<<<N / 256, 256, 0, stream>>>(best, ids16);   // also resets best
        cluster_update<<<K, 512, 0, stream>>>(feats, (const uint_t*)ids16,
                                              centroids, Bh, csq);
    }
    assign_mfma<<<(N / BM) * (K / BN), 256, 0, stream>>>(Ah, Bh, csq, best);
    convert16_kernel<<<N / 256, 256, 0, stream>>>(best, ids16);

    dist_gather<<<K, 512, 0, stream>>>(feats, centroids, (const uint_t*)ids16, dists);

    hipMemsetAsync(scal, 0, 3 * sizeof(double), stream);
    sump_kernel<<<(K * D) / 256, 256, 0, stream>>>(dists, &scal[0]);
    loss_kernel<<<(K * D) / 256, 256, 0, stream>>>(dists, &scal[0], &scal[1]);
    finalize_kernel<<<1, 1, 0, stream>>>(&scal[1], out);
}

// Round 15
// 769.548 us; speedup vs baseline: 1.8218x; 1.1499x over previous
//
#include <hip/hip_runtime.h>
#include <math.h>

#define N 16384
#define D 512
#define K 1024
#define NUM_ITERS 10
#define TEMPERATURE 0.1f
#define CONCENTRATION 0.1f
#define EPS 1e-6f

typedef unsigned short ushort_t;
typedef unsigned int uint_t;
typedef unsigned long long u64;
typedef __attribute__((ext_vector_type(4))) float floatx4;
typedef __attribute__((ext_vector_type(8))) short shortx8;

#define BM 128
#define BN 128
#define BK 64

// ---------- fp16 helpers ----------
__device__ inline ushort_t f2h(float f) {
    _Float16 h = (_Float16)f;            // RNE
    return *(ushort_t*)&h;
}

__device__ inline unsigned ford(float f) {   // order-preserving float->uint
    unsigned b = __float_as_uint(f);
    return (b & 0x80000000u) ? ~b : (b | 0x80000000u);
}

__device__ inline void f4add(float4& a, const float4& b) {
    a.x += b.x; a.y += b.y; a.z += b.z; a.w += b.w;
}

__device__ inline void gld16(const void* g, void* l) {
    __builtin_amdgcn_global_load_lds(
        (const __attribute__((address_space(1))) void*)(uintptr_t)(g),
        (__attribute__((address_space(3))) void*)(uintptr_t)(l), 16, 0, 0);
}

// ---------- cast fp32 -> fp16 (A, once) + init both best buffers ----------
__global__ void split_kernel(const float* __restrict__ x, ushort_t* __restrict__ hi,
                             u64* __restrict__ best2, int n4) {
    int i = blockIdx.x * 256 + threadIdx.x;
    if (i >= n4) return;
    float4 v = ((const float4*)x)[i];
    ushort4 hv = {f2h(v.x), f2h(v.y), f2h(v.z), f2h(v.w)};
    ((ushort4*)hi)[i] = hv;
    if (i < 2 * N) best2[i] = ~0ull;
}

// ---------- row sum-of-squares for INITIAL centroids only ----------
__global__ void rowsq_kernel(const float* __restrict__ x, float* __restrict__ out, int rows) {
    int row = blockIdx.x * 4 + (threadIdx.x >> 6);
    int lane = threadIdx.x & 63;
    if (row >= rows) return;
    const float* r = x + (size_t)row * D;
    float s = 0.f;
    for (int i = lane; i < D; i += 64) { float v = r[i]; s += v * v; }
    for (int off = 32; off > 0; off >>= 1) s += __shfl_down(s, off, 64);
    if (lane == 0) out[row] = s;
}

// ---------- MFMA assign (16x16x32 f16, single-pass, BK=64, XOR-swizzled LDS) ----------
// LDS: 8 slots/row of 16B (row stride 128B). slot(row, kb) at kb_phys = kb ^ (row&7).
// Fragment read: start banks (kb_phys*4)%32 cycle all 8 4-bank groups per 8 rows
// -> 16 lanes = 2-way aliasing = free. Staging: 8 lanes cover one row's 128B
// (coalesced); thread c stages (row=c>>3, kb=(c&7)^(row&7)) -> dest c*16B.
// K-chunk order identical to BK=32 version -> bit-identical accumulation.
__global__ __launch_bounds__(256) void assign_mfma(
    const ushort_t* __restrict__ Ah, const ushort_t* __restrict__ Bh,
    const float* __restrict__ csq, u64* __restrict__ best)
{
    __shared__ __align__(16) ushort_t sAh[BM * BK];
    __shared__ __align__(16) ushort_t sBh[BN * BK];

    const int tid = threadIdx.x;
    const int lane = tid & 63;
    const int wave = tid >> 6;
    const int wr = wave >> 1, wc = wave & 1;     // 2x2 wave grid, wave tile 64x64
    const int quad = lane >> 4, l16 = lane & 15;

    const int q = (int)blockIdx.x;
    const int xid = q & 7;
    const int s = q >> 3;
    const int brow = ((s >> 3) << 3) + xid;
    const int bcol = s & 7;
    const int row0 = brow * BM, col0 = bcol * BN;

    floatx4 acc[4][4];
#pragma unroll
    for (int a = 0; a < 4; ++a)
#pragma unroll
        for (int b = 0; b < 4; ++b) acc[a][b] = (floatx4){0.f, 0.f, 0.f, 0.f};

    // staging: slots c = i*256+tid, i=0..3; row = c>>3, kb = (c&7) ^ (row&7)
    const int r_s0 = tid >> 3;              // row for i=0 (rows advance by 32/iter)
    const int kb_s0 = tid & 7;

    for (int d0 = 0; d0 < D; d0 += BK) {
        __syncthreads();
#pragma unroll
        for (int i = 0; i < 4; ++i) {
            const int row = r_s0 + i * 32;
            const int kb = kb_s0 ^ (row & 7);
            const int dst = (i * 256 + tid) * 8;   // ushort offset = slot*8
            const size_t ga = (size_t)(row0 + row) * D + d0 + kb * 8;
            const size_t gb = (size_t)(col0 + row) * D + d0 + kb * 8;
            gld16(Ah + ga, sAh + dst);
            gld16(Bh + gb, sBh + dst);
        }
        __syncthreads();

#pragma unroll
        for (int c = 0; c < 2; ++c) {          // k-step of 32 within BK=64
            shortx8 fah[4], fbh[4];
#pragma unroll
            for (int t = 0; t < 4; ++t) {
                const int ar = wr * 64 + t * 16 + l16;
                const int bc = wc * 64 + t * 16 + l16;
                const int kbl = c * 4 + quad;
                const int qa = (kbl ^ (ar & 7)) * 8;
                const int qb = (kbl ^ (bc & 7)) * 8;
                fah[t] = *(const shortx8*)&sAh[ar * BK + qa];
                fbh[t] = *(const shortx8*)&sBh[bc * BK + qb];
            }
#pragma unroll
            for (int i = 0; i < 4; ++i)
#pragma unroll
                for (int j = 0; j < 4; ++j)
                    acc[i][j] = __builtin_amdgcn_mfma_f32_16x16x32_f16(fah[i], fbh[j], acc[i][j], 0, 0, 0);
        }
    }

    float csqv[4];
#pragma unroll
    for (int j = 0; j < 4; ++j) csqv[j] = csq[col0 + wc * 64 + j * 16 + l16];

    const int k0 = col0 + wc * 64 + l16;
#pragma unroll
    for (int i = 0; i < 4; ++i) {
#pragma unroll
        for (int r = 0; r < 4; ++r) {
            float bv = csqv[0] - 2.0f * acc[i][0][r];
            int bk = k0;
#pragma unroll
            for (int j = 1; j < 4; ++j) {
                float v = csqv[j] - 2.0f * acc[i][j][r];
                int kk = k0 + j * 16;
                if (v < bv || (v == bv && kk < bk)) { bv = v; bk = kk; }
            }
#pragma unroll
            for (int m = 1; m < 16; m <<= 1) {
                float ov = __shfl_xor(bv, m, 64);
                int ok = __shfl_xor(bk, m, 64);
                if (ov < bv || (ov == bv && ok < bk)) { bv = ov; bk = ok; }
            }
            if (l16 == 0) {
                int p = row0 + wr * 64 + i * 16 + quad * 4 + r;
                u64 pk = ((u64)ford(bv) << 32) | (unsigned)bk;
                atomicMin(&best[p], pk);
            }
        }
    }
}

// ======== round-based gather-then-process segment reduce ========
// Scans best directly (ulonglong2 = 2 packed entries/lane -> same 16
// ballot-iterations as the u16 scheme). Ping-pong: resets the OTHER best
// buffer for the next iteration (stream-ordered; R12-proven).
#define CU_WAVES 8
#define CHUNKS (N / 128)          // 128 chunks of 128 points
#define ROUNDS 4
#define WIN (CHUNKS / ROUNDS)     // 32 chunks/round
#define CPW (WIN / CU_WAVES)      // 4 chunks per wave per round

__global__ __launch_bounds__(512) void cluster_update(
    const float* __restrict__ feats, const u64* __restrict__ best,
    u64* __restrict__ best_other,
    float* __restrict__ cent, ushort_t* __restrict__ Bh,
    float* __restrict__ csq)
{
    __shared__ int list[CU_WAVES][CPW * 128];
    __shared__ int lcnt[CU_WAVES];
    __shared__ float4 part[CU_WAVES][64][2];
    __shared__ int pcnt_s[CU_WAVES];

    const int tid = threadIdx.x;
    const int lane = tid & 63;
    const int wave = tid >> 6;
    const int k = (int)blockIdx.x;

    float4 a0 = {0.f, 0.f, 0.f, 0.f}, a1 = {0.f, 0.f, 0.f, 0.f};
    int cnttot = 0;

    for (int round = 0; round < ROUNDS; ++round) {
        int cw = 0;
#pragma unroll
        for (int cc = 0; cc < CPW; ++cc) {
            int chunk = round * WIN + wave * CPW + cc;
            ulonglong2 v = ((const ulonglong2*)best)[chunk * 64 + lane];
            int id0 = (int)(uint_t)v.x;
            int id1 = (int)(uint_t)v.y;
            int p0 = chunk * 128 + 2 * lane;
            u64 m0 = __ballot(id0 == k);
            u64 m1 = __ballot(id1 == k);
            int c0 = __popcll(m0);
            u64 lanem = (1ull << lane) - 1ull;
            if (id0 == k) list[wave][cw + __popcll(m0 & lanem)] = p0;
            if (id1 == k) list[wave][cw + c0 + __popcll(m1 & lanem)] = p0 + 1;
            cw += c0 + __popcll(m1);
        }
        if (lane == 0) lcnt[wave] = cw;
        cnttot += cw;
        __syncthreads();

        int off[CU_WAVES]; int T = 0;
#pragma unroll
        for (int j = 0; j < CU_WAVES; ++j) { off[j] = T; T += lcnt[j]; }

        for (int g0 = wave; g0 < T; g0 += CU_WAVES * 4) {
            int nb = 0; int pidx[4];
#pragma unroll
            for (int b = 0; b < 4; ++b) {
                int g = g0 + CU_WAVES * b;
                if (g < T) {
                    int j = 0;
#pragma unroll
                    for (int jj = 1; jj < CU_WAVES; ++jj) if (g >= off[jj]) j = jj;
                    pidx[nb++] = list[j][g - off[j]];
                }
            }
            float4 x[4][2];
#pragma unroll
            for (int b = 0; b < 4; ++b) if (b < nb) {
                const float4* r = (const float4*)(feats + (size_t)pidx[b] * D) + lane * 2;
                x[b][0] = r[0]; x[b][1] = r[1];
            }
#pragma unroll
            for (int b = 0; b < 4; ++b) if (b < nb) {
                f4add(a0, x[b][0]); f4add(a1, x[b][1]);
            }
        }
        __syncthreads();
    }

    part[wave][lane][0] = a0; part[wave][lane][1] = a1;
    if (lane == 0) pcnt_s[wave] = cnttot;
    __syncthreads();

    if (wave == 0) {
        float4 s0 = part[0][lane][0], s1 = part[0][lane][1];
        int c = pcnt_s[0];
#pragma unroll
        for (int w = 1; w < CU_WAVES; ++w) {
            f4add(s0, part[w][lane][0]); f4add(s1, part[w][lane][1]);
            c += pcnt_s[w];
        }

        float4* crow = (float4*)(cent + (size_t)k * D) + lane * 2;
        float4 c0, c1;
        if (c > 0) {
            float cf = (float)c;
            c0 = (float4){s0.x / cf, s0.y / cf, s0.z / cf, s0.w / cf};
            c1 = (float4){s1.x / cf, s1.y / cf, s1.z / cf, s1.w / cf};
        } else {
            c0 = crow[0]; c1 = crow[1];
        }
        crow[0] = c0; crow[1] = c1;

        ushort4 hv;
        hv.x = f2h(c0.x); hv.y = f2h(c0.y); hv.z = f2h(c0.z); hv.w = f2h(c0.w);
        ((ushort4*)(Bh + (size_t)k * D))[lane * 2] = hv;
        hv.x = f2h(c1.x); hv.y = f2h(c1.y); hv.z = f2h(c1.z); hv.w = f2h(c1.w);
        ((ushort4*)(Bh + (size_t)k * D))[lane * 2 + 1] = hv;

        float s = c0.x * c0.x + c0.y * c0.y + c0.z * c0.z + c0.w * c0.w
                + c1.x * c1.x + c1.y * c1.y + c1.z * c1.z + c1.w * c1.w;
        for (int o = 32; o > 0; o >>= 1) s += __shfl_xor(s, o, 64);
        if (lane == 0) csq[k] = s;
    }

    // reset our 16-entry slice of the OTHER buffer for the next assign
    if (tid < 16) best_other[k * 16 + tid] = ~0ull;
}

// ---------- residual^2 segment sum, same scan scheme ----------
__global__ __launch_bounds__(512) void dist_gather(
    const float* __restrict__ feats, const float* __restrict__ cent,
    const u64* __restrict__ best, float* __restrict__ dists)
{
    __shared__ int list[CU_WAVES][CPW * 128];
    __shared__ int lcnt[CU_WAVES];
    __shared__ float4 part[CU_WAVES][64][2];

    const int tid = threadIdx.x;
    const int lane = tid & 63;
    const int wave = tid >> 6;
    const int k = (int)blockIdx.x;

    const float4* crow = (const float4*)(cent + (size_t)k * D) + lane * 2;
    const float4 c0 = crow[0], c1 = crow[1];

    float4 a0 = {0.f, 0.f, 0.f, 0.f}, a1 = {0.f, 0.f, 0.f, 0.f};

    for (int round = 0; round < ROUNDS; ++round) {
        int cw = 0;
#pragma unroll
        for (int cc = 0; cc < CPW; ++cc) {
            int chunk = round * WIN + wave * CPW + cc;
            ulonglong2 v = ((const ulonglong2*)best)[chunk * 64 + lane];
            int id0 = (int)(uint_t)v.x;
            int id1 = (int)(uint_t)v.y;
            int p0 = chunk * 128 + 2 * lane;
            u64 m0 = __ballot(id0 == k);
            u64 m1 = __ballot(id1 == k);
            int cc0 = __popcll(m0);
            u64 lanem = (1ull << lane) - 1ull;
            if (id0 == k) list[wave][cw + __popcll(m0 & lanem)] = p0;
            if (id1 == k) list[wave][cw + cc0 + __popcll(m1 & lanem)] = p0 + 1;
            cw += cc0 + __popcll(m1);
        }
        if (lane == 0) lcnt[wave] = cw;
        __syncthreads();

        int off[CU_WAVES]; int T = 0;
#pragma unroll
        for (int j = 0; j < CU_WAVES; ++j) { off[j] = T; T += lcnt[j]; }

        for (int g0 = wave; g0 < T; g0 += CU_WAVES * 4) {
            int nb = 0; int pidx[4];
#pragma unroll
            for (int b = 0; b < 4; ++b) {
                int g = g0 + CU_WAVES * b;
                if (g < T) {
                    int j = 0;
#pragma unroll
                    for (int jj = 1; jj < CU_WAVES; ++jj) if (g >= off[jj]) j = jj;
                    pidx[nb++] = list[j][g - off[j]];
                }
            }
            float4 x[4][2];
#pragma unroll
            for (int b = 0; b < 4; ++b) if (b < nb) {
                const float4* r = (const float4*)(feats + (size_t)pidx[b] * D) + lane * 2;
                x[b][0] = r[0]; x[b][1] = r[1];
            }
#pragma unroll
            for (int b = 0; b < 4; ++b) if (b < nb) {
                float r;
                r = x[b][0].x - c0.x; a0.x += r * r;  r = x[b][0].y - c0.y; a0.y += r * r;
                r = x[b][0].z - c0.z; a0.z += r * r;  r = x[b][0].w - c0.w; a0.w += r * r;
                r = x[b][1].x - c1.x; a1.x += r * r;  r = x[b][1].y - c1.y; a1.y += r * r;
                r = x[b][1].z - c1.z; a1.z += r * r;  r = x[b][1].w - c1.w; a1.w += r * r;
            }
        }
        __syncthreads();
    }

    part[wave][lane][0] = a0; part[wave][lane][1] = a1;
    __syncthreads();
    if (wave == 0) {
        float4 s0 = part[0][lane][0], s1 = part[0][lane][1];
#pragma unroll
        for (int w = 1; w < CU_WAVES; ++w) { f4add(s0, part[w][lane][0]); f4add(s1, part[w][lane][1]); }
        float4* drow = (float4*)(dists + (size_t)k * D) + lane * 2;
        drow[0] = s0; drow[1] = s1;
    }
}

// ---------- loss (grid-stride, 256 blocks -> 256 atomics not 2048) ----------
__global__ void sump_kernel(const float* __restrict__ dists, double* __restrict__ S) {
    int tid = threadIdx.x;
    float v = 0.f;
    for (int idx = blockIdx.x * 256 + tid; idx < K * D; idx += 256 * 256)
        v += expf(-(dists[idx] / CONCENTRATION));
    __shared__ float red[4];
    for (int off = 32; off > 0; off >>= 1) v += __shfl_down(v, off, 64);
    if ((tid & 63) == 0) red[tid >> 6] = v;
    __syncthreads();
    if (tid == 0) atomicAdd(S, (double)(red[0] + red[1] + red[2] + red[3]));
}

__global__ void loss_kernel(const float* __restrict__ dists, const double* __restrict__ Sd,
                            double* __restrict__ acc2) {
    int tid = threadIdx.x;
    float S = (float)Sd[0];
    float e = 0.f, nl = 0.f;
    for (int idx = blockIdx.x * 256 + tid; idx < K * D; idx += 256 * 256) {
        float dv = dists[idx];
        float p = expf(-(dv / CONCENTRATION));
        float qq = p / S;
        e += qq * logf(qq + EPS);
        float p2 = expf(-(dv / TEMPERATURE));
        nl += logf(p2 + EPS);
    }
    __shared__ float rede[4];
    __shared__ float redn[4];
    for (int off = 32; off > 0; off >>= 1) { e += __shfl_down(e, off, 64); nl += __shfl_down(nl, off, 64); }
    if ((tid & 63) == 0) { rede[tid >> 6] = e; redn[tid >> 6] = nl; }
    __syncthreads();
    if (tid == 0) {
        atomicAdd(&acc2[0], (double)(rede[0] + rede[1] + rede[2] + rede[3]));
        atomicAdd(&acc2[1], (double)(redn[0] + redn[1] + redn[2] + redn[3]));
    }
}

__global__ void finalize_kernel(const double* __restrict__ acc2, float* __restrict__ out) {
    double kd = (double)(K * D);
    double entropy = acc2[0] / kd;
    double nll = -(acc2[1] / kd);
    out[0] = (float)(entropy + nll);
}

extern "C" void kernel_launch(void* const* d_in, const int* in_sizes, int n_in,
                              void* d_out, int out_size, void* d_ws, size_t ws_size,
                              hipStream_t stream) {
    const float* feats = (const float*)d_in[0];
    float* out = (float*)d_out;

    ushort_t* Ah = (ushort_t*)d_ws;                  // N*D
    ushort_t* Bh = Ah + (size_t)N * D;               // K*D
    float* centroids = (float*)(Bh + (size_t)K * D); // K*D
    float* dists     = centroids + (size_t)K * D;    // K*D
    float* csq       = dists + (size_t)K * D;        // K
    u64*   best0     = (u64*)(csq + K);              // N  (contiguous with best1)
    u64*   best1     = best0 + N;                    // N
    double* scal     = (double*)(best1 + N);         // 3

    split_kernel<<<(N * D / 4) / 256, 256, 0, stream>>>(feats, Ah, best0, N * D / 4);
    hipMemcpyAsync(centroids, feats, (size_t)K * D * sizeof(float),
                   hipMemcpyDeviceToDevice, stream);
    rowsq_kernel<<<K / 4, 256, 0, stream>>>(feats, csq, K);

    for (int it = 0; it < NUM_ITERS; ++it) {
        u64* cur = (it & 1) ? best1 : best0;
        u64* oth = (it & 1) ? best0 : best1;
        const ushort_t* bh = (it == 0) ? Ah : Bh;   // iter0: init centroids = feats[:K]
        assign_mfma<<<(N / BM) * (K / BN), 256, 0, stream>>>(Ah, bh, csq, cur);
        cluster_update<<<K, 512, 0, stream>>>(feats, cur, oth, centroids, Bh, csq);
    }
    u64* fin = (NUM_ITERS & 1) ? best1 : best0;   // reset by last cluster_update
    assign_mfma<<<(N / BM) * (K / BN), 256, 0, stream>>>(Ah, Bh, csq, fin);

    dist_gather<<<K, 512, 0, stream>>>(feats, centroids, fin, dists);

    hipMemsetAsync(scal, 0, 3 * sizeof(double), stream);
    sump_kernel<<<256, 256, 0, stream>>>(dists, &scal[0]);
    loss_kernel<<<256, 256, 0, stream>>>(dists, &scal[0], &scal[1]);
    finalize_kernel<<<1, 1, 0, stream>>>(&scal[1], out);
}